// Round 2
// baseline (1248.787 us; speedup 1.0000x reference)
//
#include <hip/hip_runtime.h>
#include <hip/hip_bf16.h>

#define ND 128
#define EMB 128
#define BATCH 64
#define MM 20
#define NN 500

typedef short bf16x8 __attribute__((ext_vector_type(8)));
typedef float f32x4 __attribute__((ext_vector_type(4)));

__device__ __forceinline__ float bf2f(unsigned short u) {
    union { unsigned int i; float f; } x; x.i = ((unsigned int)u) << 16; return x.f;
}
__device__ __forceinline__ unsigned short f2bf(float f) {
    union { float f; unsigned int i; } x; x.f = f;
    unsigned int r = x.i + 0x7fffu + ((x.i >> 16) & 1u);
    return (unsigned short)(r >> 16);
}

// ---------------- CSR build ----------------
__global__ void edge_hist(const int* __restrict__ dst, int* __restrict__ cnt, int E) {
    int e = blockIdx.x * blockDim.x + threadIdx.x;
    if (e < E) atomicAdd(&cnt[dst[e]], 1);
}

__global__ void exscan32k(const int* __restrict__ cnt, int* __restrict__ rowptr, int n) {
    __shared__ int part[1024];
    int t = threadIdx.x;
    int CH = (n + 1023) >> 10;
    int beg = t * CH;
    int s = 0;
    for (int i = 0; i < CH; ++i) { int idx = beg + i; if (idx < n) s += cnt[idx]; }
    part[t] = s; __syncthreads();
    for (int off = 1; off < 1024; off <<= 1) {
        int v = (t >= off) ? part[t - off] : 0;
        __syncthreads();
        part[t] += v;
        __syncthreads();
    }
    int run = (t > 0) ? part[t - 1] : 0;
    for (int i = 0; i < CH; ++i) { int idx = beg + i; if (idx < n) { rowptr[idx] = run; run += cnt[idx]; } }
    if (t == 1023) rowptr[n] = part[1023];
}

__global__ void edge_scatter(const int* __restrict__ src, const int* __restrict__ dst,
                             const int* __restrict__ rowptr, int* __restrict__ fill,
                             int* __restrict__ col, int E) {
    int e = blockIdx.x * blockDim.x + threadIdx.x;
    if (e < E) {
        int d = dst[e];
        int p = atomicAdd(&fill[d], 1);
        col[rowptr[d] + p] = src[e];
    }
}

// ---------------- fused weight build ----------------
// Wf[384][128] fp32 -> hi/lo bf16.  Rows 0..127: lw. Rows 128..255: Ai@lw (ui, bias=Ai@lb+ab).
// Rows 256..383: Aj@lw (uj, bias=Aj@lb).  Ai = aw[:, :128], Aj = aw[:, 128:].
__global__ void make_wc(const float* __restrict__ lw, const float* __restrict__ lb,
                        const float* __restrict__ aw, const float* __restrict__ ab,
                        unsigned short* __restrict__ Whi, unsigned short* __restrict__ Wlo,
                        float* __restrict__ bfc) {
    int n = blockIdx.x;   // 0..383
    int e = threadIdx.x;  // 0..127
    float w;
    if (n < 128) {
        w = lw[n * 128 + e];
    } else if (n < 256) {
        int ni = n - 128; float s = 0.f;
        for (int k = 0; k < 128; ++k) s += aw[ni * 256 + k] * lw[k * 128 + e];
        w = s;
    } else {
        int nj = n - 256; float s = 0.f;
        for (int k = 0; k < 128; ++k) s += aw[nj * 256 + 128 + k] * lw[k * 128 + e];
        w = s;
    }
    unsigned short hi = f2bf(w);
    Whi[n * 128 + e] = hi;
    Wlo[n * 128 + e] = f2bf(w - bf2f(hi));
    if (e == 0) {
        float b;
        if (n < 128) b = lb[n];
        else if (n < 256) {
            int ni = n - 128; float s = ab[ni];
            for (int k = 0; k < 128; ++k) s += aw[ni * 256 + k] * lb[k];
            b = s;
        } else {
            int nj = n - 256; float s = 0.f;
            for (int k = 0; k < 128; ++k) s += aw[nj * 256 + 128 + k] * lb[k];
            b = s;
        }
        bfc[n] = b;
    }
}

// ---------------- fused GEMM: out[M][384] = fp32(X[M][128] @ Wf[384][128]^T + bias) ----------------
// Split-precision: X=Xhi+Xlo, W=Whi+Wlo; acc += Xhi*Whi + Xlo*Whi + Xhi*Wlo  (~fp32 exact).
// gridDim.y = 6 slabs of 64 output cols; one 16-row tile per wave.
__launch_bounds__(256, 2)
__global__ void lin_fused(const float* __restrict__ X,
                          const unsigned short* __restrict__ Whi,
                          const unsigned short* __restrict__ Wlo,
                          const float* __restrict__ bias,
                          float* __restrict__ out, int M) {
    const int slab = blockIdx.y;  // 0..5
    const int lane = threadIdx.x & 63;
    const int wv = threadIdx.x >> 6;
    const int r16 = lane & 15;
    const int quad = lane >> 4;
    const int gw = blockIdx.x * 4 + wv;
    const int nw = gridDim.x * 4;

    const unsigned short* Wh = Whi + (size_t)slab * 64 * 128;
    const unsigned short* Wl = Wlo + (size_t)slab * 64 * 128;
    bf16x8 wh[4][4], wl[4][4];
#pragma unroll
    for (int nt = 0; nt < 4; ++nt)
#pragma unroll
        for (int ks = 0; ks < 4; ++ks) {
            wh[nt][ks] = *(const bf16x8*)(Wh + (nt * 16 + r16) * 128 + ks * 32 + quad * 8);
            wl[nt][ks] = *(const bf16x8*)(Wl + (nt * 16 + r16) * 128 + ks * 32 + quad * 8);
        }
    float bv[4];
#pragma unroll
    for (int nt = 0; nt < 4; ++nt) bv[nt] = bias[slab * 64 + nt * 16 + r16];

    const int mt_count = M >> 4;
    for (int mt = gw; mt < mt_count; mt += nw) {
        bf16x8 ah[4], al[4];
#pragma unroll
        for (int ks = 0; ks < 4; ++ks) {
            const float* xp = X + (size_t)(mt * 16 + r16) * 128 + ks * 32 + quad * 8;
            float4 v0 = *(const float4*)xp;
            float4 v1 = *(const float4*)(xp + 4);
            float v[8] = {v0.x, v0.y, v0.z, v0.w, v1.x, v1.y, v1.z, v1.w};
#pragma unroll
            for (int j = 0; j < 8; ++j) {
                unsigned short h = f2bf(v[j]);
                ah[ks][j] = (short)h;
                al[ks][j] = (short)f2bf(v[j] - bf2f(h));
            }
        }
#pragma unroll
        for (int nt = 0; nt < 4; ++nt) {
            f32x4 acc = {bv[nt], bv[nt], bv[nt], bv[nt]};
#pragma unroll
            for (int ks = 0; ks < 4; ++ks) {
                acc = __builtin_amdgcn_mfma_f32_16x16x32_bf16(ah[ks], wh[nt][ks], acc, 0, 0, 0);
                acc = __builtin_amdgcn_mfma_f32_16x16x32_bf16(al[ks], wh[nt][ks], acc, 0, 0, 0);
                acc = __builtin_amdgcn_mfma_f32_16x16x32_bf16(ah[ks], wl[nt][ks], acc, 0, 0, 0);
            }
#pragma unroll
            for (int r = 0; r < 4; ++r) {
                int row = mt * 16 + quad * 4 + r;
                out[(size_t)row * 384 + slab * 64 + nt * 16 + r16] = acc[r];
            }
        }
    }
}

// ---------------- GAT aggregation: one wave per dst node, online softmax, fp32 ----------------
// hu row layout (384 floats): [h(128) | ui'(128, incl ab) | uj(128)]
__global__ void gat_agg(const float* __restrict__ hu,
                        const int* __restrict__ rowptr, const int* __restrict__ col,
                        const float* __restrict__ resid,
                        float* __restrict__ out, int N) {
    int wid = (int)((blockIdx.x * blockDim.x + threadIdx.x) >> 6);
    if (wid >= N) return;
    int lane = threadIdx.x & 63;
    const float2* hu2 = (const float2*)hu;  // row stride 192 float2

    float2 uiv = hu2[(size_t)wid * 192 + 64 + lane];
    float2 ujs = hu2[(size_t)wid * 192 + 128 + lane];
    float2 hs  = hu2[(size_t)wid * 192 + lane];

    float a0 = uiv.x + ujs.x; a0 = a0 > 0.f ? a0 : 0.2f * a0;
    float a1 = uiv.y + ujs.y; a1 = a1 > 0.f ? a1 : 0.2f * a1;
    float m0 = a0, m1 = a1, l0 = 1.f, l1 = 1.f;
    float acc0 = hs.x, acc1 = hs.y;

    int e = rowptr[wid], end = rowptr[wid + 1];
    for (; e < end; ++e) {
        int s = col[e];
        float2 uj = hu2[(size_t)s * 192 + 128 + lane];
        float2 hj = hu2[(size_t)s * 192 + lane];
        float b0 = uiv.x + uj.x; b0 = b0 > 0.f ? b0 : 0.2f * b0;
        float b1 = uiv.y + uj.y; b1 = b1 > 0.f ? b1 : 0.2f * b1;
        float n0 = fmaxf(m0, b0), n1 = fmaxf(m1, b1);
        float s0 = __expf(m0 - n0), s1 = __expf(m1 - n1);
        float p0 = __expf(b0 - n0), p1 = __expf(b1 - n1);
        l0 = l0 * s0 + p0;            l1 = l1 * s1 + p1;
        acc0 = acc0 * s0 + hj.x * p0; acc1 = acc1 * s1 + hj.y * p1;
        m0 = n0; m1 = n1;
    }
    float o0 = acc0 / (l0 + 1e-16f);
    float o1 = acc1 / (l1 + 1e-16f);
    if (resid) {
        float2 rv = ((const float2*)resid)[(size_t)wid * 64 + lane];
        o0 += rv.x; o1 += rv.y;
    }
    ((float2*)out)[(size_t)wid * 64 + lane] = make_float2(o0, o1);
}

// ---------------- GRU (fp32, one block of 128 per batch row) ----------------
__global__ void gru_kernel(const float* __restrict__ st_, const float* __restrict__ in_,
                           const float* __restrict__ win,
                           const float* __restrict__ wz, const float* __restrict__ bz,
                           const float* __restrict__ wr, const float* __restrict__ br,
                           const float* __restrict__ wh, const float* __restrict__ bh,
                           float* __restrict__ out) {
    __shared__ float sst[ND], sib[EMB], si[ND], srs[ND];
    int b = blockIdx.x, d = threadIdx.x;
    float s = 0.f;
    for (int m = 0; m < MM; ++m) s += in_[((size_t)b * MM + m) * EMB + d];
    sib[d] = s * (1.0f / MM);
    sst[d] = st_[b * ND + d];
    __syncthreads();
    float iv = 0.f;
    for (int e = 0; e < EMB; ++e) iv += sib[e] * win[d * EMB + e];
    si[d] = iv;
    __syncthreads();
    float za = bz[d], ra = br[d];
    for (int e = 0; e < ND; ++e) {
        za += sst[e] * wz[d * 2 * ND + e] + si[e] * wz[d * 2 * ND + ND + e];
        ra += sst[e] * wr[d * 2 * ND + e] + si[e] * wr[d * 2 * ND + ND + e];
    }
    float z = 1.f / (1.f + __expf(-za));
    float r = 1.f / (1.f + __expf(-ra));
    srs[d] = r * sst[d];
    __syncthreads();
    float ha = bh[d];
    for (int e = 0; e < ND; ++e)
        ha += srs[e] * wh[d * 2 * ND + e] + si[e] * wh[d * 2 * ND + ND + e];
    float hc = tanhf(ha);
    out[b * ND + d] = (1.f - z) * sst[d] + z * hc;
}

// ---------------- heads: softmax + elu heads (fp32), one block per batch row ----------------
__global__ void heads_kernel(const float* __restrict__ gx,
                             const float* __restrict__ pw_, const float* __restrict__ pb_,
                             const float* __restrict__ mw_, const float* __restrict__ mb_,
                             const float* __restrict__ sw_, const float* __restrict__ sbias_,
                             float* __restrict__ out) {
    __shared__ float scs[NN - 1], sas[NN - 1], sbs[NN - 1], red[256];
    int b = blockIdx.x;
    int tid = threadIdx.x;
    int lane = tid & 63, wv = tid >> 6;
    const float2* g2 = (const float2*)gx;
    float2 pwv = ((const float2*)pw_)[lane];
    float2 mwv = ((const float2*)mw_)[lane];
    float2 swv = ((const float2*)sw_)[lane];
    for (int t = wv; t < NN - 1; t += 4) {
        int node = b * NN + 1 + t;
        float2 xv = g2[(size_t)node * 64 + lane];
        float dp = xv.x * pwv.x + xv.y * pwv.y;
        float dm = xv.x * mwv.x + xv.y * mwv.y;
        float ds = xv.x * swv.x + xv.y * swv.y;
        for (int off = 32; off; off >>= 1) {
            dp += __shfl_xor(dp, off);
            dm += __shfl_xor(dm, off);
            ds += __shfl_xor(ds, off);
        }
        if (lane == 0) { scs[t] = dp + pb_[0]; sas[t] = dm; sbs[t] = ds; }
    }
    __syncthreads();
    float mx = -1e30f;
    for (int t = tid; t < NN - 1; t += 256) mx = fmaxf(mx, scs[t]);
    red[tid] = mx; __syncthreads();
    for (int off = 128; off; off >>= 1) { if (tid < off) red[tid] = fmaxf(red[tid], red[tid + off]); __syncthreads(); }
    mx = red[0];
    __syncthreads();
    float sum = 0.f;
    for (int t = tid; t < NN - 1; t += 256) { float e = __expf(scs[t] - mx); scs[t] = e; sum += e; }
    __syncthreads();
    red[tid] = sum; __syncthreads();
    for (int off = 128; off; off >>= 1) { if (tid < off) red[tid] += red[tid + off]; __syncthreads(); }
    float inv = 1.0f / red[0];
    float mbv = mb_[0], sbv = sbias_[0];
    float* oP = out + BATCH * ND + (size_t)b * (NN - 1);
    float* oA = out + BATCH * ND + (size_t)BATCH * (NN - 1) + (size_t)b * (NN - 1);
    float* oB = out + BATCH * ND + 2 * (size_t)BATCH * (NN - 1) + (size_t)b * (NN - 1);
    for (int t = tid; t < NN - 1; t += 256) {
        oP[t] = scs[t] * inv;
        float av = sas[t] + mbv; av = av > 0.f ? av : (__expf(av) - 1.f);
        oA[t] = av + 2.f;
        float bv = fabsf(sbs[t] + sbv);  // elu(|x|) == |x|
        oB[t] = bv + 2.f;
    }
}

extern "C" void kernel_launch(void* const* d_in, const int* in_sizes, int n_in,
                              void* d_out, int out_size, void* d_ws, size_t ws_size,
                              hipStream_t stream) {
    const float* state_ = (const float*)d_in[0];
    const float* input_ = (const float*)d_in[1];
    const float* x      = (const float*)d_in[2];
    const int* e_n  = (const int*)d_in[3];
    const int* e_r0 = (const int*)d_in[4];
    const int* e_r1 = (const int*)d_in[5];
    const float* win = (const float*)d_in[7];
    const float* wz  = (const float*)d_in[8];
    const float* bz  = (const float*)d_in[9];
    const float* wr  = (const float*)d_in[10];
    const float* br  = (const float*)d_in[11];
    const float* wh  = (const float*)d_in[12];
    const float* bh  = (const float*)d_in[13];
    const float* g0_lw = (const float*)d_in[14];
    const float* g0_lb = (const float*)d_in[15];
    const float* g0_aw = (const float*)d_in[16];
    const float* g0_ab = (const float*)d_in[17];
    const float* g1_lw = (const float*)d_in[18];
    const float* g1_lb = (const float*)d_in[19];
    const float* g1_aw = (const float*)d_in[20];
    const float* g1_ab = (const float*)d_in[21];
    const float* g2_lw = (const float*)d_in[22];
    const float* g2_lb = (const float*)d_in[23];
    const float* g2_aw = (const float*)d_in[24];
    const float* g2_ab = (const float*)d_in[25];
    const float* gn_lw = (const float*)d_in[26];
    const float* gn_lb = (const float*)d_in[27];
    const float* gn_aw = (const float*)d_in[28];
    const float* gn_ab = (const float*)d_in[29];
    const float* pw = (const float*)d_in[30];
    const float* pb = (const float*)d_in[31];
    const float* mw = (const float*)d_in[32];
    const float* mb = (const float*)d_in[33];
    const float* sw = (const float*)d_in[34];
    const float* sb = (const float*)d_in[35];
    float* out = (float*)d_out;

    const int E = in_sizes[3] / 2;    // 256000
    const int N = in_sizes[2] / EMB;  // 32000

    // workspace carve-up (~103 MB)
    char* w = (char*)d_ws;
    auto alloc = [&](size_t bytes) { char* p = w; w += (bytes + 255) & ~(size_t)255; return p; };
    int* rp[3];   for (int i = 0; i < 3; ++i) rp[i]   = (int*)alloc((size_t)(N + 1) * sizeof(int));
    int* colv[3]; for (int i = 0; i < 3; ++i) colv[i] = (int*)alloc((size_t)E * sizeof(int));
    int* tmp = (int*)alloc(3 * (size_t)N * sizeof(int));
    unsigned short* Whi[4]; unsigned short* Wlo[4]; float* Bf[4];
    for (int i = 0; i < 4; ++i) {
        Whi[i] = (unsigned short*)alloc(384 * 128 * 2);
        Wlo[i] = (unsigned short*)alloc(384 * 128 * 2);
        Bf[i]  = (float*)alloc(384 * 4);
    }
    float* hu = (float*)alloc((size_t)N * 384 * 4);
    float* ga = (float*)alloc((size_t)N * 128 * 4);
    float* gb = (float*)alloc((size_t)N * 128 * 4);
    float* gc = (float*)alloc((size_t)N * 128 * 4);

    const int* elists[3] = {e_n, e_r0, e_r1};

    // CSR build (dst-sorted) for the 3 edge lists
    hipMemsetAsync(tmp, 0, 3 * (size_t)N * sizeof(int), stream);
    for (int i = 0; i < 3; ++i)
        edge_hist<<<(E + 255) / 256, 256, 0, stream>>>(elists[i] + E, tmp + (size_t)i * N, E);
    for (int i = 0; i < 3; ++i)
        exscan32k<<<1, 1024, 0, stream>>>(tmp + (size_t)i * N, rp[i], N);
    hipMemsetAsync(tmp, 0, 3 * (size_t)N * sizeof(int), stream);
    for (int i = 0; i < 3; ++i)
        edge_scatter<<<(E + 255) / 256, 256, 0, stream>>>(elists[i], elists[i] + E, rp[i], tmp + (size_t)i * N, colv[i], E);

    // fused weights (4 sets: g0, g1, g2, gn)
    make_wc<<<384, 128, 0, stream>>>(g0_lw, g0_lb, g0_aw, g0_ab, Whi[0], Wlo[0], Bf[0]);
    make_wc<<<384, 128, 0, stream>>>(g1_lw, g1_lb, g1_aw, g1_ab, Whi[1], Wlo[1], Bf[1]);
    make_wc<<<384, 128, 0, stream>>>(g2_lw, g2_lb, g2_aw, g2_ab, Whi[2], Wlo[2], Bf[2]);
    make_wc<<<384, 128, 0, stream>>>(gn_lw, gn_lb, gn_aw, gn_ab, Whi[3], Wlo[3], Bf[3]);

    // GRU head (output 0, fp32 exact)
    gru_kernel<<<BATCH, ND, 0, stream>>>(state_, input_, win, wz, bz, wr, br, wh, bh, out);

    auto conv = [&](const float* in, int csr_i, int wi, const float* resid, float* o) {
        lin_fused<<<dim3((N / 16 + 3) / 4, 6), 256, 0, stream>>>(in, Whi[wi], Wlo[wi], Bf[wi], hu, N);
        gat_agg<<<(N * 64) / 256, 256, 0, stream>>>(hu, rp[csr_i], colv[csr_i], resid, o, N);
    };

    conv(x,  0, 0, nullptr, ga);  // g0 (e_n)
    conv(ga, 2, 1, nullptr, gb);  // g1 (e_r1)
    conv(gb, 2, 1, nullptr, gc);  // g2 (e_r1, g1 weights)
    conv(gc, 0, 3, ga,      gb);  // g3 = conv(g2, e_n, gn) + g0
    conv(gb, 1, 2, nullptr, gc);  // g4 (e_r0, g2 weights)
    conv(gc, 1, 2, nullptr, ga);  // g5 (e_r0, g2 weights)
    conv(ga, 0, 3, gb,      gc);  // gx = conv(g5, e_n, gn) + g3

    heads_kernel<<<BATCH, 256, 0, stream>>>(gc, pw, pb, mw, mb, sw, sb, out);
}

// Round 3
// 1020.266 us; speedup vs baseline: 1.2240x; 1.2240x over previous
//
#include <hip/hip_runtime.h>
#include <hip/hip_bf16.h>

#define ND 128
#define EMB 128
#define BATCH 64
#define MM 20
#define NN 500

typedef short bf16x8 __attribute__((ext_vector_type(8)));
typedef float f32x4 __attribute__((ext_vector_type(4)));

__device__ __forceinline__ float bf2f(unsigned short u) {
    union { unsigned int i; float f; } x; x.i = ((unsigned int)u) << 16; return x.f;
}
__device__ __forceinline__ unsigned short f2bf(float f) {
    union { float f; unsigned int i; } x; x.f = f;
    unsigned int r = x.i + 0x7fffu + ((x.i >> 16) & 1u);
    return (unsigned short)(r >> 16);
}

// ---------------- CSR build (fused over the 3 edge lists) ----------------
struct EdgePtrs { const int* e[3]; };

__global__ void edge_hist3(EdgePtrs ep, int* __restrict__ cnt, int E, int N) {
    int li = blockIdx.y;
    const int* dst = ep.e[li] + E;
    int e = blockIdx.x * blockDim.x + threadIdx.x;
    if (e < E) atomicAdd(&cnt[(size_t)li * N + dst[e]], 1);
}

__global__ void exscan3(const int* __restrict__ cnt, int* __restrict__ rowptr, int n) {
    __shared__ int part[1024];
    int li = blockIdx.x;
    const int* c = cnt + (size_t)li * n;
    int* rp = rowptr + (size_t)li * (n + 1);
    int t = threadIdx.x;
    int CH = (n + 1023) >> 10;
    int beg = t * CH;
    int s = 0;
    for (int i = 0; i < CH; ++i) { int idx = beg + i; if (idx < n) s += c[idx]; }
    part[t] = s; __syncthreads();
    for (int off = 1; off < 1024; off <<= 1) {
        int v = (t >= off) ? part[t - off] : 0;
        __syncthreads();
        part[t] += v;
        __syncthreads();
    }
    int run = (t > 0) ? part[t - 1] : 0;
    for (int i = 0; i < CH; ++i) { int idx = beg + i; if (idx < n) { rp[idx] = run; run += c[idx]; } }
    if (t == 1023) rp[n] = part[1023];
}

__global__ void edge_scatter3(EdgePtrs ep, const int* __restrict__ rowptr, int* __restrict__ fill,
                              int* __restrict__ col, int E, int N) {
    int li = blockIdx.y;
    const int* src = ep.e[li];
    const int* dst = src + E;
    const int* rp = rowptr + (size_t)li * (N + 1);
    int e = blockIdx.x * blockDim.x + threadIdx.x;
    if (e < E) {
        int d = dst[e];
        int p = atomicAdd(&fill[(size_t)li * N + d], 1);
        col[(size_t)li * E + rp[d] + p] = src[e];
    }
}

// ---------------- fused weight build (all 4 weight sets in one launch) ----------------
// Wf[384][128] fp32 -> hi/lo bf16.  Rows 0..127: lw. Rows 128..255: Ai@lw (bias=Ai@lb+ab).
// Rows 256..383: Aj@lw (bias=Aj@lb).  Ai = aw[:, :128], Aj = aw[:, 128:].
struct WcPtrs {
    const float* lw[4]; const float* lb[4]; const float* aw[4]; const float* ab[4];
    unsigned short* Whi[4]; unsigned short* Wlo[4]; float* Bf[4];
};

__global__ void make_wc4(WcPtrs p) {
    int set = blockIdx.y;
    const float* lw = p.lw[set]; const float* lb = p.lb[set];
    const float* aw = p.aw[set]; const float* ab = p.ab[set];
    int n = blockIdx.x;   // 0..383
    int e = threadIdx.x;  // 0..127
    float w;
    if (n < 128) {
        w = lw[n * 128 + e];
    } else if (n < 256) {
        int ni = n - 128; float s = 0.f;
        for (int k = 0; k < 128; ++k) s += aw[ni * 256 + k] * lw[k * 128 + e];
        w = s;
    } else {
        int nj = n - 256; float s = 0.f;
        for (int k = 0; k < 128; ++k) s += aw[nj * 256 + 128 + k] * lw[k * 128 + e];
        w = s;
    }
    unsigned short hi = f2bf(w);
    p.Whi[set][n * 128 + e] = hi;
    p.Wlo[set][n * 128 + e] = f2bf(w - bf2f(hi));
    if (e == 0) {
        float b;
        if (n < 128) b = lb[n];
        else if (n < 256) {
            int ni = n - 128; float s = ab[ni];
            for (int k = 0; k < 128; ++k) s += aw[ni * 256 + k] * lb[k];
            b = s;
        } else {
            int nj = n - 256; float s = 0.f;
            for (int k = 0; k < 128; ++k) s += aw[nj * 256 + 128 + k] * lb[k];
            b = s;
        }
        p.Bf[set][n] = b;
    }
}

// ---------------- fused GEMM: out[M][384] = fp32(X[M][128] @ Wf[384][128]^T + bias) ----------------
// Split-precision: X=Xhi+Xlo, W=Whi+Wlo; acc += Xhi*Whi + Xlo*Whi + Xhi*Wlo  (~fp32 exact).
__launch_bounds__(256, 2)
__global__ void lin_fused(const float* __restrict__ X,
                          const unsigned short* __restrict__ Whi,
                          const unsigned short* __restrict__ Wlo,
                          const float* __restrict__ bias,
                          float* __restrict__ out, int M) {
    const int slab = blockIdx.y;  // 0..5
    const int lane = threadIdx.x & 63;
    const int wv = threadIdx.x >> 6;
    const int r16 = lane & 15;
    const int quad = lane >> 4;
    const int gw = blockIdx.x * 4 + wv;
    const int nw = gridDim.x * 4;

    const unsigned short* Wh = Whi + (size_t)slab * 64 * 128;
    const unsigned short* Wl = Wlo + (size_t)slab * 64 * 128;
    bf16x8 wh[4][4], wl[4][4];
#pragma unroll
    for (int nt = 0; nt < 4; ++nt)
#pragma unroll
        for (int ks = 0; ks < 4; ++ks) {
            wh[nt][ks] = *(const bf16x8*)(Wh + (nt * 16 + r16) * 128 + ks * 32 + quad * 8);
            wl[nt][ks] = *(const bf16x8*)(Wl + (nt * 16 + r16) * 128 + ks * 32 + quad * 8);
        }
    float bv[4];
#pragma unroll
    for (int nt = 0; nt < 4; ++nt) bv[nt] = bias[slab * 64 + nt * 16 + r16];

    const int mt_count = M >> 4;
    for (int mt = gw; mt < mt_count; mt += nw) {
        bf16x8 ah[4], al[4];
#pragma unroll
        for (int ks = 0; ks < 4; ++ks) {
            const float* xp = X + (size_t)(mt * 16 + r16) * 128 + ks * 32 + quad * 8;
            float4 v0 = *(const float4*)xp;
            float4 v1 = *(const float4*)(xp + 4);
            float v[8] = {v0.x, v0.y, v0.z, v0.w, v1.x, v1.y, v1.z, v1.w};
#pragma unroll
            for (int j = 0; j < 8; ++j) {
                unsigned short h = f2bf(v[j]);
                ah[ks][j] = (short)h;
                al[ks][j] = (short)f2bf(v[j] - bf2f(h));
            }
        }
#pragma unroll
        for (int nt = 0; nt < 4; ++nt) {
            f32x4 acc = {bv[nt], bv[nt], bv[nt], bv[nt]};
#pragma unroll
            for (int ks = 0; ks < 4; ++ks) {
                acc = __builtin_amdgcn_mfma_f32_16x16x32_bf16(ah[ks], wh[nt][ks], acc, 0, 0, 0);
                acc = __builtin_amdgcn_mfma_f32_16x16x32_bf16(al[ks], wh[nt][ks], acc, 0, 0, 0);
                acc = __builtin_amdgcn_mfma_f32_16x16x32_bf16(ah[ks], wl[nt][ks], acc, 0, 0, 0);
            }
#pragma unroll
            for (int r = 0; r < 4; ++r) {
                int row = mt * 16 + quad * 4 + r;
                out[(size_t)row * 384 + slab * 64 + nt * 16 + r16] = acc[r];
            }
        }
    }
}

// ---------------- GAT aggregation: one wave per dst node, online softmax, fp32 ----------------
// hu row layout (384 floats): [h(128) | ui'(128, incl ab) | uj(128)]
__global__ void gat_agg(const float* __restrict__ hu,
                        const int* __restrict__ rowptr, const int* __restrict__ col,
                        const float* __restrict__ resid,
                        float* __restrict__ out, int N) {
    int wid = (int)((blockIdx.x * blockDim.x + threadIdx.x) >> 6);
    if (wid >= N) return;
    int lane = threadIdx.x & 63;
    const float2* hu2 = (const float2*)hu;  // row stride 192 float2

    float2 uiv = hu2[(size_t)wid * 192 + 64 + lane];
    float2 ujs = hu2[(size_t)wid * 192 + 128 + lane];
    float2 hs  = hu2[(size_t)wid * 192 + lane];

    float a0 = uiv.x + ujs.x; a0 = a0 > 0.f ? a0 : 0.2f * a0;
    float a1 = uiv.y + ujs.y; a1 = a1 > 0.f ? a1 : 0.2f * a1;
    float m0 = a0, m1 = a1, l0 = 1.f, l1 = 1.f;
    float acc0 = hs.x, acc1 = hs.y;

#define AGG_STEP(uj, hj)                                                  \
    {                                                                     \
        float b0 = uiv.x + uj.x; b0 = b0 > 0.f ? b0 : 0.2f * b0;          \
        float b1 = uiv.y + uj.y; b1 = b1 > 0.f ? b1 : 0.2f * b1;          \
        float n0 = fmaxf(m0, b0), n1 = fmaxf(m1, b1);                     \
        float s0 = __expf(m0 - n0), s1 = __expf(m1 - n1);                 \
        float p0 = __expf(b0 - n0), p1 = __expf(b1 - n1);                 \
        l0 = l0 * s0 + p0;            l1 = l1 * s1 + p1;                  \
        acc0 = acc0 * s0 + hj.x * p0; acc1 = acc1 * s1 + hj.y * p1;       \
        m0 = n0; m1 = n1;                                                 \
    }

    int e = rowptr[wid], end = rowptr[wid + 1];
    for (; e + 2 <= end; e += 2) {
        int sA = col[e], sB = col[e + 1];
        float2 ujA = hu2[(size_t)sA * 192 + 128 + lane];
        float2 hjA = hu2[(size_t)sA * 192 + lane];
        float2 ujB = hu2[(size_t)sB * 192 + 128 + lane];
        float2 hjB = hu2[(size_t)sB * 192 + lane];
        AGG_STEP(ujA, hjA);
        AGG_STEP(ujB, hjB);
    }
    if (e < end) {
        int sA = col[e];
        float2 ujA = hu2[(size_t)sA * 192 + 128 + lane];
        float2 hjA = hu2[(size_t)sA * 192 + lane];
        AGG_STEP(ujA, hjA);
    }
#undef AGG_STEP

    float o0 = acc0 / (l0 + 1e-16f);
    float o1 = acc1 / (l1 + 1e-16f);
    if (resid) {
        float2 rv = ((const float2*)resid)[(size_t)wid * 64 + lane];
        o0 += rv.x; o1 += rv.y;
    }
    ((float2*)out)[(size_t)wid * 64 + lane] = make_float2(o0, o1);
}

// ---------------- GRU (fp32, one block of 128 per batch row) ----------------
__global__ void gru_kernel(const float* __restrict__ st_, const float* __restrict__ in_,
                           const float* __restrict__ win,
                           const float* __restrict__ wz, const float* __restrict__ bz,
                           const float* __restrict__ wr, const float* __restrict__ br,
                           const float* __restrict__ wh, const float* __restrict__ bh,
                           float* __restrict__ out) {
    __shared__ float sst[ND], sib[EMB], si[ND], srs[ND];
    int b = blockIdx.x, d = threadIdx.x;
    float s = 0.f;
    for (int m = 0; m < MM; ++m) s += in_[((size_t)b * MM + m) * EMB + d];
    sib[d] = s * (1.0f / MM);
    sst[d] = st_[b * ND + d];
    __syncthreads();
    float iv = 0.f;
    for (int e = 0; e < EMB; ++e) iv += sib[e] * win[d * EMB + e];
    si[d] = iv;
    __syncthreads();
    float za = bz[d], ra = br[d];
    for (int e = 0; e < ND; ++e) {
        za += sst[e] * wz[d * 2 * ND + e] + si[e] * wz[d * 2 * ND + ND + e];
        ra += sst[e] * wr[d * 2 * ND + e] + si[e] * wr[d * 2 * ND + ND + e];
    }
    float z = 1.f / (1.f + __expf(-za));
    float r = 1.f / (1.f + __expf(-ra));
    srs[d] = r * sst[d];
    __syncthreads();
    float ha = bh[d];
    for (int e = 0; e < ND; ++e)
        ha += srs[e] * wh[d * 2 * ND + e] + si[e] * wh[d * 2 * ND + ND + e];
    float hc = tanhf(ha);
    out[b * ND + d] = (1.f - z) * sst[d] + z * hc;
}

// ---------------- heads phase 1: wave-per-node dots + elu outputs + staged scores ----------------
// grid (NN-1, 16), block 256 (4 waves): b = blockIdx.y*4 + wave, t = blockIdx.x.
__global__ void heads_dots(const float* __restrict__ gx,
                           const float* __restrict__ pw_,
                           const float* __restrict__ mw_, const float* __restrict__ mb_,
                           const float* __restrict__ sw_, const float* __restrict__ sbias_,
                           float* __restrict__ scores, float* __restrict__ out) {
    int t = blockIdx.x;
    int lane = threadIdx.x & 63;
    int b = blockIdx.y * 4 + (threadIdx.x >> 6);
    const float2* g2 = (const float2*)gx;
    float2 pwv = ((const float2*)pw_)[lane];
    float2 mwv = ((const float2*)mw_)[lane];
    float2 swv = ((const float2*)sw_)[lane];
    int node = b * NN + 1 + t;
    float2 xv = g2[(size_t)node * 64 + lane];
    float dp = xv.x * pwv.x + xv.y * pwv.y;
    float dm = xv.x * mwv.x + xv.y * mwv.y;
    float ds = xv.x * swv.x + xv.y * swv.y;
    for (int off = 32; off; off >>= 1) {
        dp += __shfl_xor(dp, off);
        dm += __shfl_xor(dm, off);
        ds += __shfl_xor(ds, off);
    }
    if (lane == 0) {
        scores[(size_t)b * (NN - 1) + t] = dp;  // pb cancels in softmax
        float av = dm + mb_[0]; av = av > 0.f ? av : (__expf(av) - 1.f);
        float bv = fabsf(ds + sbias_[0]);       // elu(|x|) == |x|
        float* oA = out + BATCH * ND + (size_t)BATCH * (NN - 1);
        float* oB = oA + (size_t)BATCH * (NN - 1);
        oA[(size_t)b * (NN - 1) + t] = av + 2.f;
        oB[(size_t)b * (NN - 1) + t] = bv + 2.f;
    }
}

// ---------------- heads phase 2: softmax over 499 per batch row ----------------
__global__ void heads_softmax(const float* __restrict__ scores, float* __restrict__ out) {
    __shared__ float scs[NN - 1], red[256];
    int b = blockIdx.x, tid = threadIdx.x;
    float mx = -1e30f;
    for (int t = tid; t < NN - 1; t += 256) { float v = scores[(size_t)b * (NN - 1) + t]; scs[t] = v; mx = fmaxf(mx, v); }
    red[tid] = mx; __syncthreads();
    for (int off = 128; off; off >>= 1) { if (tid < off) red[tid] = fmaxf(red[tid], red[tid + off]); __syncthreads(); }
    mx = red[0]; __syncthreads();
    float sum = 0.f;
    for (int t = tid; t < NN - 1; t += 256) { float e = __expf(scs[t] - mx); scs[t] = e; sum += e; }
    red[tid] = sum; __syncthreads();
    for (int off = 128; off; off >>= 1) { if (tid < off) red[tid] += red[tid + off]; __syncthreads(); }
    float inv = 1.0f / red[0];
    float* oP = out + BATCH * ND + (size_t)b * (NN - 1);
    for (int t = tid; t < NN - 1; t += 256) oP[t] = scs[t] * inv;
}

extern "C" void kernel_launch(void* const* d_in, const int* in_sizes, int n_in,
                              void* d_out, int out_size, void* d_ws, size_t ws_size,
                              hipStream_t stream) {
    const float* state_ = (const float*)d_in[0];
    const float* input_ = (const float*)d_in[1];
    const float* x      = (const float*)d_in[2];
    const int* e_n  = (const int*)d_in[3];
    const int* e_r0 = (const int*)d_in[4];
    const int* e_r1 = (const int*)d_in[5];
    const float* win = (const float*)d_in[7];
    const float* wz  = (const float*)d_in[8];
    const float* bz  = (const float*)d_in[9];
    const float* wr  = (const float*)d_in[10];
    const float* br  = (const float*)d_in[11];
    const float* wh  = (const float*)d_in[12];
    const float* bh  = (const float*)d_in[13];
    const float* pw = (const float*)d_in[30];
    const float* mw = (const float*)d_in[32];
    const float* mb = (const float*)d_in[33];
    const float* sw = (const float*)d_in[34];
    const float* sb = (const float*)d_in[35];
    float* out = (float*)d_out;

    const int E = in_sizes[3] / 2;    // 256000
    const int N = in_sizes[2] / EMB;  // 32000

    // workspace carve-up (~103 MB)
    char* w = (char*)d_ws;
    auto alloc = [&](size_t bytes) { char* p = w; w += (bytes + 255) & ~(size_t)255; return p; };
    int* rpbase = (int*)alloc(3 * (size_t)(N + 1) * sizeof(int));
    int* colbase = (int*)alloc(3 * (size_t)E * sizeof(int));
    int* tmp = (int*)alloc(3 * (size_t)N * sizeof(int));
    unsigned short* Whi[4]; unsigned short* Wlo[4]; float* Bf[4];
    for (int i = 0; i < 4; ++i) {
        Whi[i] = (unsigned short*)alloc(384 * 128 * 2);
        Wlo[i] = (unsigned short*)alloc(384 * 128 * 2);
        Bf[i]  = (float*)alloc(384 * 4);
    }
    float* hu = (float*)alloc((size_t)N * 384 * 4);
    float* ga = (float*)alloc((size_t)N * 128 * 4);
    float* gb = (float*)alloc((size_t)N * 128 * 4);
    float* gc = (float*)alloc((size_t)N * 128 * 4);
    float* scores = (float*)alloc((size_t)BATCH * (NN - 1) * 4);

    EdgePtrs ep; ep.e[0] = e_n; ep.e[1] = e_r0; ep.e[2] = e_r1;

    // CSR build (dst-sorted) for the 3 edge lists — fused launches
    hipMemsetAsync(tmp, 0, 3 * (size_t)N * sizeof(int), stream);
    edge_hist3<<<dim3((E + 255) / 256, 3), 256, 0, stream>>>(ep, tmp, E, N);
    exscan3<<<3, 1024, 0, stream>>>(tmp, rpbase, N);
    hipMemsetAsync(tmp, 0, 3 * (size_t)N * sizeof(int), stream);
    edge_scatter3<<<dim3((E + 255) / 256, 3), 256, 0, stream>>>(ep, rpbase, tmp, colbase, E, N);

    // fused weights (4 sets: g0, g1, g2, gn) in one launch
    WcPtrs wp;
    wp.lw[0] = (const float*)d_in[14]; wp.lb[0] = (const float*)d_in[15];
    wp.aw[0] = (const float*)d_in[16]; wp.ab[0] = (const float*)d_in[17];
    wp.lw[1] = (const float*)d_in[18]; wp.lb[1] = (const float*)d_in[19];
    wp.aw[1] = (const float*)d_in[20]; wp.ab[1] = (const float*)d_in[21];
    wp.lw[2] = (const float*)d_in[22]; wp.lb[2] = (const float*)d_in[23];
    wp.aw[2] = (const float*)d_in[24]; wp.ab[2] = (const float*)d_in[25];
    wp.lw[3] = (const float*)d_in[26]; wp.lb[3] = (const float*)d_in[27];
    wp.aw[3] = (const float*)d_in[28]; wp.ab[3] = (const float*)d_in[29];
    for (int i = 0; i < 4; ++i) { wp.Whi[i] = Whi[i]; wp.Wlo[i] = Wlo[i]; wp.Bf[i] = Bf[i]; }
    make_wc4<<<dim3(384, 4), 128, 0, stream>>>(wp);

    // GRU head (output 0, fp32 exact)
    gru_kernel<<<BATCH, ND, 0, stream>>>(state_, input_, win, wz, bz, wr, br, wh, bh, out);

    auto conv = [&](const float* in, int csr_i, int wi, const float* resid, float* o) {
        lin_fused<<<dim3(500, 6), 256, 0, stream>>>(in, Whi[wi], Wlo[wi], Bf[wi], hu, N);
        gat_agg<<<(N * 64) / 256, 256, 0, stream>>>(hu, rpbase + (size_t)csr_i * (N + 1),
                                                    colbase + (size_t)csr_i * E, resid, o, N);
    };

    conv(x,  0, 0, nullptr, ga);  // g0 (e_n)
    conv(ga, 2, 1, nullptr, gb);  // g1 (e_r1)
    conv(gb, 2, 1, nullptr, gc);  // g2 (e_r1, g1 weights)
    conv(gc, 0, 3, ga,      gb);  // g3 = conv(g2, e_n, gn) + g0
    conv(gb, 1, 2, nullptr, gc);  // g4 (e_r0, g2 weights)
    conv(gc, 1, 2, nullptr, ga);  // g5 (e_r0, g2 weights)
    conv(ga, 0, 3, gb,      gc);  // gx = conv(g5, e_n, gn) + g3

    heads_dots<<<dim3(NN - 1, 16), 256, 0, stream>>>(gc, pw, mw, mb, sw, sb, scores, out);
    heads_softmax<<<BATCH, 256, 0, stream>>>(scores, out);
}

// Round 4
// 816.591 us; speedup vs baseline: 1.5293x; 1.2494x over previous
//
#include <hip/hip_runtime.h>
#include <hip/hip_bf16.h>

#define ND 128
#define EMB 128
#define BATCH 64
#define MM 20
#define NN 500

typedef short bf16x8 __attribute__((ext_vector_type(8)));
typedef float f32x4 __attribute__((ext_vector_type(4)));

__device__ __forceinline__ float bf2f(unsigned short u) {
    union { unsigned int i; float f; } x; x.i = ((unsigned int)u) << 16; return x.f;
}
__device__ __forceinline__ unsigned short f2bf(float f) {
    union { float f; unsigned int i; } x; x.f = f;
    unsigned int r = x.i + 0x7fffu + ((x.i >> 16) & 1u);
    return (unsigned short)(r >> 16);
}

// ---------------- CSR build (fused over the 3 edge lists) ----------------
struct EdgePtrs { const int* e[3]; };

__global__ void edge_hist3(EdgePtrs ep, int* __restrict__ cnt, int E, int N) {
    int li = blockIdx.y;
    const int* dst = ep.e[li] + E;
    int e = blockIdx.x * blockDim.x + threadIdx.x;
    if (e < E) atomicAdd(&cnt[(size_t)li * N + dst[e]], 1);
}

__global__ void exscan3(const int* __restrict__ cnt, int* __restrict__ rowptr, int n) {
    __shared__ int part[1024];
    int li = blockIdx.x;
    const int* c = cnt + (size_t)li * n;
    int* rp = rowptr + (size_t)li * (n + 1);
    int t = threadIdx.x;
    int CH = (n + 1023) >> 10;
    int beg = t * CH;
    int s = 0;
    for (int i = 0; i < CH; ++i) { int idx = beg + i; if (idx < n) s += c[idx]; }
    part[t] = s; __syncthreads();
    for (int off = 1; off < 1024; off <<= 1) {
        int v = (t >= off) ? part[t - off] : 0;
        __syncthreads();
        part[t] += v;
        __syncthreads();
    }
    int run = (t > 0) ? part[t - 1] : 0;
    for (int i = 0; i < CH; ++i) { int idx = beg + i; if (idx < n) { rp[idx] = run; run += c[idx]; } }
    if (t == 1023) rp[n] = part[1023];
}

__global__ void edge_scatter3(EdgePtrs ep, const int* __restrict__ rowptr, int* __restrict__ fill,
                              int* __restrict__ col, int E, int N) {
    int li = blockIdx.y;
    const int* src = ep.e[li];
    const int* dst = src + E;
    const int* rp = rowptr + (size_t)li * (N + 1);
    int e = blockIdx.x * blockDim.x + threadIdx.x;
    if (e < E) {
        int d = dst[e];
        int p = atomicAdd(&fill[(size_t)li * N + d], 1);
        col[(size_t)li * E + rp[d] + p] = src[e];
    }
}

// ---------------- fused weight build (all 4 weight sets in one launch) ----------------
struct WcPtrs {
    const float* lw[4]; const float* lb[4]; const float* aw[4]; const float* ab[4];
    unsigned short* Whi[4]; unsigned short* Wlo[4]; float* Bf[4];
};

__global__ void make_wc4(WcPtrs p) {
    int set = blockIdx.y;
    const float* lw = p.lw[set]; const float* lb = p.lb[set];
    const float* aw = p.aw[set]; const float* ab = p.ab[set];
    int n = blockIdx.x;   // 0..383
    int e = threadIdx.x;  // 0..127
    float w;
    if (n < 128) {
        w = lw[n * 128 + e];
    } else if (n < 256) {
        int ni = n - 128; float s = 0.f;
        for (int k = 0; k < 128; ++k) s += aw[ni * 256 + k] * lw[k * 128 + e];
        w = s;
    } else {
        int nj = n - 256; float s = 0.f;
        for (int k = 0; k < 128; ++k) s += aw[nj * 256 + 128 + k] * lw[k * 128 + e];
        w = s;
    }
    unsigned short hi = f2bf(w);
    p.Whi[set][n * 128 + e] = hi;
    p.Wlo[set][n * 128 + e] = f2bf(w - bf2f(hi));
    if (e == 0) {
        float b;
        if (n < 128) b = lb[n];
        else if (n < 256) {
            int ni = n - 128; float s = ab[ni];
            for (int k = 0; k < 128; ++k) s += aw[ni * 256 + k] * lb[k];
            b = s;
        } else {
            int nj = n - 256; float s = 0.f;
            for (int k = 0; k < 128; ++k) s += aw[nj * 256 + 128 + k] * lb[k];
            b = s;
        }
        p.Bf[set][n] = b;
    }
}

// ---------------- fused GEMM: out[M][384] = fp32(X[M][128] @ Wf[384][128]^T + bias) ----------------
// Split-precision: X=Xhi+Xlo, W=Whi+Wlo; acc += Xhi*Whi + Xlo*Whi + Xhi*Wlo  (~fp32 exact).
// grid (64, 6): W fragments stay in registers across ~8 row-tiles per wave.
__launch_bounds__(256, 2)
__global__ void lin_fused(const float* __restrict__ X,
                          const unsigned short* __restrict__ Whi,
                          const unsigned short* __restrict__ Wlo,
                          const float* __restrict__ bias,
                          float* __restrict__ out, int M) {
    const int slab = blockIdx.y;  // 0..5
    const int lane = threadIdx.x & 63;
    const int wv = threadIdx.x >> 6;
    const int r16 = lane & 15;
    const int quad = lane >> 4;
    const int gw = blockIdx.x * 4 + wv;
    const int nw = gridDim.x * 4;

    const unsigned short* Wh = Whi + (size_t)slab * 64 * 128;
    const unsigned short* Wl = Wlo + (size_t)slab * 64 * 128;
    bf16x8 wh[4][4], wl[4][4];
#pragma unroll
    for (int nt = 0; nt < 4; ++nt)
#pragma unroll
        for (int ks = 0; ks < 4; ++ks) {
            wh[nt][ks] = *(const bf16x8*)(Wh + (nt * 16 + r16) * 128 + ks * 32 + quad * 8);
            wl[nt][ks] = *(const bf16x8*)(Wl + (nt * 16 + r16) * 128 + ks * 32 + quad * 8);
        }
    float bv[4];
#pragma unroll
    for (int nt = 0; nt < 4; ++nt) bv[nt] = bias[slab * 64 + nt * 16 + r16];

    const int mt_count = M >> 4;
    for (int mt = gw; mt < mt_count; mt += nw) {
        bf16x8 ah[4], al[4];
#pragma unroll
        for (int ks = 0; ks < 4; ++ks) {
            const float* xp = X + (size_t)(mt * 16 + r16) * 128 + ks * 32 + quad * 8;
            float4 v0 = *(const float4*)xp;
            float4 v1 = *(const float4*)(xp + 4);
            float v[8] = {v0.x, v0.y, v0.z, v0.w, v1.x, v1.y, v1.z, v1.w};
#pragma unroll
            for (int j = 0; j < 8; ++j) {
                unsigned short h = f2bf(v[j]);
                ah[ks][j] = (short)h;
                al[ks][j] = (short)f2bf(v[j] - bf2f(h));
            }
        }
#pragma unroll
        for (int nt = 0; nt < 4; ++nt) {
            f32x4 acc = {bv[nt], bv[nt], bv[nt], bv[nt]};
#pragma unroll
            for (int ks = 0; ks < 4; ++ks) {
                acc = __builtin_amdgcn_mfma_f32_16x16x32_bf16(ah[ks], wh[nt][ks], acc, 0, 0, 0);
                acc = __builtin_amdgcn_mfma_f32_16x16x32_bf16(al[ks], wh[nt][ks], acc, 0, 0, 0);
                acc = __builtin_amdgcn_mfma_f32_16x16x32_bf16(ah[ks], wl[nt][ks], acc, 0, 0, 0);
            }
#pragma unroll
            for (int r = 0; r < 4; ++r) {
                int row = mt * 16 + quad * 4 + r;
                out[(size_t)row * 384 + slab * 64 + nt * 16 + r16] = acc[r];
            }
        }
    }
}

// ---------------- GAT aggregation: one wave per dst node, online softmax, fp32 ----------------
// hu row layout (384 floats): [h(128) | ui'(128, incl ab) | uj(128)]
__global__ void gat_agg(const float* __restrict__ hu,
                        const int* __restrict__ rowptr, const int* __restrict__ col,
                        const float* __restrict__ resid,
                        float* __restrict__ out, int N) {
    int wid = (int)((blockIdx.x * blockDim.x + threadIdx.x) >> 6);
    if (wid >= N) return;
    int lane = threadIdx.x & 63;
    const float2* hu2 = (const float2*)hu;  // row stride 192 float2

    float2 uiv = hu2[(size_t)wid * 192 + 64 + lane];
    float2 ujs = hu2[(size_t)wid * 192 + 128 + lane];
    float2 hs  = hu2[(size_t)wid * 192 + lane];

    float a0 = uiv.x + ujs.x; a0 = a0 > 0.f ? a0 : 0.2f * a0;
    float a1 = uiv.y + ujs.y; a1 = a1 > 0.f ? a1 : 0.2f * a1;
    float m0 = a0, m1 = a1, l0 = 1.f, l1 = 1.f;
    float acc0 = hs.x, acc1 = hs.y;

#define AGG_STEP(uj, hj)                                                  \
    {                                                                     \
        float b0 = uiv.x + uj.x; b0 = b0 > 0.f ? b0 : 0.2f * b0;          \
        float b1 = uiv.y + uj.y; b1 = b1 > 0.f ? b1 : 0.2f * b1;          \
        float n0 = fmaxf(m0, b0), n1 = fmaxf(m1, b1);                     \
        float s0 = __expf(m0 - n0), s1 = __expf(m1 - n1);                 \
        float p0 = __expf(b0 - n0), p1 = __expf(b1 - n1);                 \
        l0 = l0 * s0 + p0;            l1 = l1 * s1 + p1;                  \
        acc0 = acc0 * s0 + hj.x * p0; acc1 = acc1 * s1 + hj.y * p1;       \
        m0 = n0; m1 = n1;                                                 \
    }

    int e = rowptr[wid], end = rowptr[wid + 1];
    for (; e + 4 <= end; e += 4) {
        int sA = col[e], sB = col[e + 1], sC = col[e + 2], sD = col[e + 3];
        float2 ujA = hu2[(size_t)sA * 192 + 128 + lane];
        float2 hjA = hu2[(size_t)sA * 192 + lane];
        float2 ujB = hu2[(size_t)sB * 192 + 128 + lane];
        float2 hjB = hu2[(size_t)sB * 192 + lane];
        float2 ujC = hu2[(size_t)sC * 192 + 128 + lane];
        float2 hjC = hu2[(size_t)sC * 192 + lane];
        float2 ujD = hu2[(size_t)sD * 192 + 128 + lane];
        float2 hjD = hu2[(size_t)sD * 192 + lane];
        AGG_STEP(ujA, hjA);
        AGG_STEP(ujB, hjB);
        AGG_STEP(ujC, hjC);
        AGG_STEP(ujD, hjD);
    }
    for (; e < end; ++e) {
        int sA = col[e];
        float2 ujA = hu2[(size_t)sA * 192 + 128 + lane];
        float2 hjA = hu2[(size_t)sA * 192 + lane];
        AGG_STEP(ujA, hjA);
    }
#undef AGG_STEP

    float o0 = acc0 / (l0 + 1e-16f);
    float o1 = acc1 / (l1 + 1e-16f);
    if (resid) {
        float2 rv = ((const float2*)resid)[(size_t)wid * 64 + lane];
        o0 += rv.x; o1 += rv.y;
    }
    ((float2*)out)[(size_t)wid * 64 + lane] = make_float2(o0, o1);
}

// ---------------- GRU (fp32, one block of 128 per batch row) ----------------
__global__ void gru_kernel(const float* __restrict__ st_, const float* __restrict__ in_,
                           const float* __restrict__ win,
                           const float* __restrict__ wz, const float* __restrict__ bz,
                           const float* __restrict__ wr, const float* __restrict__ br,
                           const float* __restrict__ wh, const float* __restrict__ bh,
                           float* __restrict__ out) {
    __shared__ float sst[ND], sib[EMB], si[ND], srs[ND];
    int b = blockIdx.x, d = threadIdx.x;
    float s = 0.f;
    for (int m = 0; m < MM; ++m) s += in_[((size_t)b * MM + m) * EMB + d];
    sib[d] = s * (1.0f / MM);
    sst[d] = st_[b * ND + d];
    __syncthreads();
    float iv = 0.f;
    for (int e = 0; e < EMB; ++e) iv += sib[e] * win[d * EMB + e];
    si[d] = iv;
    __syncthreads();
    float za = bz[d], ra = br[d];
    for (int e = 0; e < ND; ++e) {
        za += sst[e] * wz[d * 2 * ND + e] + si[e] * wz[d * 2 * ND + ND + e];
        ra += sst[e] * wr[d * 2 * ND + e] + si[e] * wr[d * 2 * ND + ND + e];
    }
    float z = 1.f / (1.f + __expf(-za));
    float r = 1.f / (1.f + __expf(-ra));
    srs[d] = r * sst[d];
    __syncthreads();
    float ha = bh[d];
    for (int e = 0; e < ND; ++e)
        ha += srs[e] * wh[d * 2 * ND + e] + si[e] * wh[d * 2 * ND + ND + e];
    float hc = tanhf(ha);
    out[b * ND + d] = (1.f - z) * sst[d] + z * hc;
}

// ---------------- heads phase 1: wave-per-node dots + elu outputs + staged scores ----------------
__global__ void heads_dots(const float* __restrict__ gx,
                           const float* __restrict__ pw_,
                           const float* __restrict__ mw_, const float* __restrict__ mb_,
                           const float* __restrict__ sw_, const float* __restrict__ sbias_,
                           float* __restrict__ scores, float* __restrict__ out) {
    int t = blockIdx.x;
    int lane = threadIdx.x & 63;
    int b = blockIdx.y * 4 + (threadIdx.x >> 6);
    const float2* g2 = (const float2*)gx;
    float2 pwv = ((const float2*)pw_)[lane];
    float2 mwv = ((const float2*)mw_)[lane];
    float2 swv = ((const float2*)sw_)[lane];
    int node = b * NN + 1 + t;
    float2 xv = g2[(size_t)node * 64 + lane];
    float dp = xv.x * pwv.x + xv.y * pwv.y;
    float dm = xv.x * mwv.x + xv.y * mwv.y;
    float ds = xv.x * swv.x + xv.y * swv.y;
    for (int off = 32; off; off >>= 1) {
        dp += __shfl_xor(dp, off);
        dm += __shfl_xor(dm, off);
        ds += __shfl_xor(ds, off);
    }
    if (lane == 0) {
        scores[(size_t)b * (NN - 1) + t] = dp;  // pb cancels in softmax
        float av = dm + mb_[0]; av = av > 0.f ? av : (__expf(av) - 1.f);
        float bv = fabsf(ds + sbias_[0]);       // elu(|x|) == |x|
        float* oA = out + BATCH * ND + (size_t)BATCH * (NN - 1);
        float* oB = oA + (size_t)BATCH * (NN - 1);
        oA[(size_t)b * (NN - 1) + t] = av + 2.f;
        oB[(size_t)b * (NN - 1) + t] = bv + 2.f;
    }
}

// ---------------- heads phase 2: softmax over 499 per batch row ----------------
__global__ void heads_softmax(const float* __restrict__ scores, float* __restrict__ out) {
    __shared__ float scs[NN - 1], red[256];
    int b = blockIdx.x, tid = threadIdx.x;
    float mx = -1e30f;
    for (int t = tid; t < NN - 1; t += 256) { float v = scores[(size_t)b * (NN - 1) + t]; scs[t] = v; mx = fmaxf(mx, v); }
    red[tid] = mx; __syncthreads();
    for (int off = 128; off; off >>= 1) { if (tid < off) red[tid] = fmaxf(red[tid], red[tid + off]); __syncthreads(); }
    mx = red[0]; __syncthreads();
    float sum = 0.f;
    for (int t = tid; t < NN - 1; t += 256) { float e = __expf(scs[t] - mx); scs[t] = e; sum += e; }
    red[tid] = sum; __syncthreads();
    for (int off = 128; off; off >>= 1) { if (tid < off) red[tid] += red[tid + off]; __syncthreads(); }
    float inv = 1.0f / red[0];
    float* oP = out + BATCH * ND + (size_t)b * (NN - 1);
    for (int t = tid; t < NN - 1; t += 256) oP[t] = scs[t] * inv;
}

extern "C" void kernel_launch(void* const* d_in, const int* in_sizes, int n_in,
                              void* d_out, int out_size, void* d_ws, size_t ws_size,
                              hipStream_t stream) {
    const float* state_ = (const float*)d_in[0];
    const float* input_ = (const float*)d_in[1];
    const float* x      = (const float*)d_in[2];
    const int* e_n  = (const int*)d_in[3];
    const int* e_r0 = (const int*)d_in[4];
    const int* e_r1 = (const int*)d_in[5];
    const float* win = (const float*)d_in[7];
    const float* wz  = (const float*)d_in[8];
    const float* bz  = (const float*)d_in[9];
    const float* wr  = (const float*)d_in[10];
    const float* br  = (const float*)d_in[11];
    const float* wh  = (const float*)d_in[12];
    const float* bh  = (const float*)d_in[13];
    const float* pw = (const float*)d_in[30];
    const float* mw = (const float*)d_in[32];
    const float* mb = (const float*)d_in[33];
    const float* sw = (const float*)d_in[34];
    const float* sb = (const float*)d_in[35];
    float* out = (float*)d_out;

    const int E = in_sizes[3] / 2;    // 256000
    const int N = in_sizes[2] / EMB;  // 32000

    char* w = (char*)d_ws;
    auto alloc = [&](size_t bytes) { char* p = w; w += (bytes + 255) & ~(size_t)255; return p; };
    int* rpbase = (int*)alloc(3 * (size_t)(N + 1) * sizeof(int));
    int* colbase = (int*)alloc(3 * (size_t)E * sizeof(int));
    int* tmp = (int*)alloc(3 * (size_t)N * sizeof(int));
    unsigned short* Whi[4]; unsigned short* Wlo[4]; float* Bf[4];
    for (int i = 0; i < 4; ++i) {
        Whi[i] = (unsigned short*)alloc(384 * 128 * 2);
        Wlo[i] = (unsigned short*)alloc(384 * 128 * 2);
        Bf[i]  = (float*)alloc(384 * 4);
    }
    float* hu = (float*)alloc((size_t)N * 384 * 4);
    float* ga = (float*)alloc((size_t)N * 128 * 4);
    float* gb = (float*)alloc((size_t)N * 128 * 4);
    float* gc = (float*)alloc((size_t)N * 128 * 4);
    float* scores = (float*)alloc((size_t)BATCH * (NN - 1) * 4);

    EdgePtrs ep; ep.e[0] = e_n; ep.e[1] = e_r0; ep.e[2] = e_r1;

    hipMemsetAsync(tmp, 0, 3 * (size_t)N * sizeof(int), stream);
    edge_hist3<<<dim3((E + 255) / 256, 3), 256, 0, stream>>>(ep, tmp, E, N);
    exscan3<<<3, 1024, 0, stream>>>(tmp, rpbase, N);
    hipMemsetAsync(tmp, 0, 3 * (size_t)N * sizeof(int), stream);
    edge_scatter3<<<dim3((E + 255) / 256, 3), 256, 0, stream>>>(ep, rpbase, tmp, colbase, E, N);

    WcPtrs wp;
    wp.lw[0] = (const float*)d_in[14]; wp.lb[0] = (const float*)d_in[15];
    wp.aw[0] = (const float*)d_in[16]; wp.ab[0] = (const float*)d_in[17];
    wp.lw[1] = (const float*)d_in[18]; wp.lb[1] = (const float*)d_in[19];
    wp.aw[1] = (const float*)d_in[20]; wp.ab[1] = (const float*)d_in[21];
    wp.lw[2] = (const float*)d_in[22]; wp.lb[2] = (const float*)d_in[23];
    wp.aw[2] = (const float*)d_in[24]; wp.ab[2] = (const float*)d_in[25];
    wp.lw[3] = (const float*)d_in[26]; wp.lb[3] = (const float*)d_in[27];
    wp.aw[3] = (const float*)d_in[28]; wp.ab[3] = (const float*)d_in[29];
    for (int i = 0; i < 4; ++i) { wp.Whi[i] = Whi[i]; wp.Wlo[i] = Wlo[i]; wp.Bf[i] = Bf[i]; }
    make_wc4<<<dim3(384, 4), 128, 0, stream>>>(wp);

    gru_kernel<<<BATCH, ND, 0, stream>>>(state_, input_, win, wz, bz, wr, br, wh, bh, out);

    auto conv = [&](const float* in, int csr_i, int wi, const float* resid, float* o) {
        lin_fused<<<dim3(64, 6), 256, 0, stream>>>(in, Whi[wi], Wlo[wi], Bf[wi], hu, N);
        gat_agg<<<(N * 64) / 256, 256, 0, stream>>>(hu, rpbase + (size_t)csr_i * (N + 1),
                                                    colbase + (size_t)csr_i * E, resid, o, N);
    };

    conv(x,  0, 0, nullptr, ga);  // g0 (e_n)
    conv(ga, 2, 1, nullptr, gb);  // g1 (e_r1)
    conv(gb, 2, 1, nullptr, gc);  // g2 (e_r1, g1 weights)
    conv(gc, 0, 3, ga,      gb);  // g3 = conv(g2, e_n, gn) + g0
    conv(gb, 1, 2, nullptr, gc);  // g4 (e_r0, g2 weights)
    conv(gc, 1, 2, nullptr, ga);  // g5 (e_r0, g2 weights)
    conv(ga, 0, 3, gb,      gc);  // gx = conv(g5, e_n, gn) + g3

    heads_dots<<<dim3(NN - 1, 16), 256, 0, stream>>>(gc, pw, mw, mb, sw, sb, scores, out);
    heads_softmax<<<BATCH, 256, 0, stream>>>(scores, out);
}

// Round 5
// 660.999 us; speedup vs baseline: 1.8892x; 1.2354x over previous
//
#include <hip/hip_runtime.h>
#include <hip/hip_bf16.h>

#define ND 128
#define EMB 128
#define BATCH 64
#define MM 20
#define NN 500
#define RPAD 8   // rowptr row stride padding so each row is 16-B aligned

typedef short bf16x8 __attribute__((ext_vector_type(8)));
typedef float f32x4 __attribute__((ext_vector_type(4)));

__device__ __forceinline__ float bf2f(unsigned short u) {
    union { unsigned int i; float f; } x; x.i = ((unsigned int)u) << 16; return x.f;
}
__device__ __forceinline__ unsigned short f2bf(float f) {
    union { float f; unsigned int i; } x; x.f = f;
    unsigned int r = x.i + 0x7fffu + ((x.i >> 16) & 1u);
    return (unsigned short)(r >> 16);
}
__device__ __forceinline__ float2 bfpair(unsigned int p) {
    union { unsigned int i; float f; } a, b;
    a.i = p << 16; b.i = p & 0xffff0000u;
    return make_float2(a.f, b.f);
}

// ---------------- CSR build (fused over the 3 edge lists) ----------------
struct EdgePtrs { const int* e[3]; };

__global__ void edge_hist3(EdgePtrs ep, int* __restrict__ cnt, int E, int N) {
    int li = blockIdx.y;
    const int* dst = ep.e[li] + E;
    int e = blockIdx.x * blockDim.x + threadIdx.x;
    if (e < E) atomicAdd(&cnt[(size_t)li * N + dst[e]], 1);
}

// vectorized + wave-shuffle exclusive scan; grid = 3 blocks x 1024 threads.
__global__ void exscan3(const int* __restrict__ cnt, int* __restrict__ rowptr, int n) {
    __shared__ int wsum[16];
    __shared__ int woff[16];
    int li = blockIdx.x;
    const int4* c4 = (const int4*)(cnt + (size_t)li * n);
    int* rp = rowptr + (size_t)li * (n + RPAD);
    int t = threadIdx.x;
    int lane = t & 63, wid = t >> 6;
    int n4 = n >> 2;  // n % 4 == 0

    int4 v[8];
    int s = 0;
#pragma unroll
    for (int i = 0; i < 8; ++i) {
        int idx = t * 8 + i;
        if (idx < n4) v[i] = c4[idx];
        else { v[i].x = v[i].y = v[i].z = v[i].w = 0; }
    }
#pragma unroll
    for (int i = 0; i < 8; ++i) s += v[i].x + v[i].y + v[i].z + v[i].w;

    // wave inclusive scan (no barriers)
    int ps = s;
#pragma unroll
    for (int d = 1; d < 64; d <<= 1) {
        int u = __shfl_up(ps, d, 64);
        if (lane >= d) ps += u;
    }
    if (lane == 63) wsum[wid] = ps;
    __syncthreads();
    if (t == 0) {
        int r = 0;
        for (int i = 0; i < 16; ++i) { woff[i] = r; r += wsum[i]; }
    }
    __syncthreads();
    int run = woff[wid] + ps - s;  // exclusive prefix of this thread's chunk
    int4* rp4 = (int4*)rp;
#pragma unroll
    for (int i = 0; i < 8; ++i) {
        int idx = t * 8 + i;
        if (idx < n4) {
            int4 o;
            o.x = run; run += v[i].x;
            o.y = run; run += v[i].y;
            o.z = run; run += v[i].z;
            o.w = run; run += v[i].w;
            rp4[idx] = o;
        }
    }
    if (t == (n - 1) / 32) rp[n] = run;
}

__global__ void edge_scatter3(EdgePtrs ep, const int* __restrict__ rowptr, int* __restrict__ fill,
                              int* __restrict__ col, int E, int N) {
    int li = blockIdx.y;
    const int* src = ep.e[li];
    const int* dst = src + E;
    const int* rp = rowptr + (size_t)li * (N + RPAD);
    int e = blockIdx.x * blockDim.x + threadIdx.x;
    if (e < E) {
        int d = dst[e];
        int p = atomicAdd(&fill[(size_t)li * N + d], 1);
        col[(size_t)li * E + rp[d] + p] = src[e];
    }
}

// ---------------- fused weight build (all 4 weight sets in one launch) ----------------
struct WcPtrs {
    const float* lw[4]; const float* lb[4]; const float* aw[4]; const float* ab[4];
    unsigned short* Whi[4]; unsigned short* Wlo[4]; float* Bf[4];
};

__global__ void make_wc4(WcPtrs p) {
    int set = blockIdx.y;
    const float* lw = p.lw[set]; const float* lb = p.lb[set];
    const float* aw = p.aw[set]; const float* ab = p.ab[set];
    int n = blockIdx.x;   // 0..383
    int e = threadIdx.x;  // 0..127
    float w;
    if (n < 128) {
        w = lw[n * 128 + e];
    } else if (n < 256) {
        int ni = n - 128; float s = 0.f;
        for (int k = 0; k < 128; ++k) s += aw[ni * 256 + k] * lw[k * 128 + e];
        w = s;
    } else {
        int nj = n - 256; float s = 0.f;
        for (int k = 0; k < 128; ++k) s += aw[nj * 256 + 128 + k] * lw[k * 128 + e];
        w = s;
    }
    unsigned short hi = f2bf(w);
    p.Whi[set][n * 128 + e] = hi;
    p.Wlo[set][n * 128 + e] = f2bf(w - bf2f(hi));
    if (e == 0) {
        float b;
        if (n < 128) b = lb[n];
        else if (n < 256) {
            int ni = n - 128; float s = ab[ni];
            for (int k = 0; k < 128; ++k) s += aw[ni * 256 + k] * lb[k];
            b = s;
        } else {
            int nj = n - 256; float s = 0.f;
            for (int k = 0; k < 128; ++k) s += aw[nj * 256 + 128 + k] * lb[k];
            b = s;
        }
        p.Bf[set][n] = b;
    }
}

// ---------------- fused GEMM into packed hu ----------------
// hu row (1024 B): P slab = 256 bf16 shorts, 64 groups [h2l,h2l+1,uj2l,uj2l+1];
//                  U slab = 128 fp32 floats (ui', incl ab).
// Split-precision: acc += Xhi*Whi + Xlo*Whi + Xhi*Wlo  (~fp32 exact).
__launch_bounds__(256, 2)
__global__ void lin_fused(const float* __restrict__ X,
                          const unsigned short* __restrict__ Whi,
                          const unsigned short* __restrict__ Wlo,
                          const float* __restrict__ bias,
                          void* __restrict__ hu, int M) {
    const int slab = blockIdx.y;  // 0..5: 0,1=h  2,3=ui  4,5=uj
    const int lane = threadIdx.x & 63;
    const int wv = threadIdx.x >> 6;
    const int r16 = lane & 15;
    const int quad = lane >> 4;
    const int gw = blockIdx.x * 4 + wv;
    const int nw = gridDim.x * 4;

    unsigned short* hu16 = (unsigned short*)hu;  // row stride 512 shorts
    float* huf = (float*)hu;                     // row stride 256 floats

    const unsigned short* Wh = Whi + (size_t)slab * 64 * 128;
    const unsigned short* Wl = Wlo + (size_t)slab * 64 * 128;
    bf16x8 wh[4][4], wl[4][4];
#pragma unroll
    for (int nt = 0; nt < 4; ++nt)
#pragma unroll
        for (int ks = 0; ks < 4; ++ks) {
            wh[nt][ks] = *(const bf16x8*)(Wh + (nt * 16 + r16) * 128 + ks * 32 + quad * 8);
            wl[nt][ks] = *(const bf16x8*)(Wl + (nt * 16 + r16) * 128 + ks * 32 + quad * 8);
        }
    float bv[4];
#pragma unroll
    for (int nt = 0; nt < 4; ++nt) bv[nt] = bias[slab * 64 + nt * 16 + r16];

    const int mt_count = M >> 4;
    for (int mt = gw; mt < mt_count; mt += nw) {
        bf16x8 ah[4], al[4];
#pragma unroll
        for (int ks = 0; ks < 4; ++ks) {
            const float* xp = X + (size_t)(mt * 16 + r16) * 128 + ks * 32 + quad * 8;
            float4 v0 = *(const float4*)xp;
            float4 v1 = *(const float4*)(xp + 4);
            float v[8] = {v0.x, v0.y, v0.z, v0.w, v1.x, v1.y, v1.z, v1.w};
#pragma unroll
            for (int j = 0; j < 8; ++j) {
                unsigned short h = f2bf(v[j]);
                ah[ks][j] = (short)h;
                al[ks][j] = (short)f2bf(v[j] - bf2f(h));
            }
        }
#pragma unroll
        for (int nt = 0; nt < 4; ++nt) {
            f32x4 acc = {bv[nt], bv[nt], bv[nt], bv[nt]};
#pragma unroll
            for (int ks = 0; ks < 4; ++ks) {
                acc = __builtin_amdgcn_mfma_f32_16x16x32_bf16(ah[ks], wh[nt][ks], acc, 0, 0, 0);
                acc = __builtin_amdgcn_mfma_f32_16x16x32_bf16(al[ks], wh[nt][ks], acc, 0, 0, 0);
                acc = __builtin_amdgcn_mfma_f32_16x16x32_bf16(ah[ks], wl[nt][ks], acc, 0, 0, 0);
            }
            int col = slab * 64 + nt * 16 + r16;
#pragma unroll
            for (int r = 0; r < 4; ++r) {
                size_t row = (size_t)(mt * 16 + quad * 4 + r);
                if (slab < 2) {
                    int c = col;
                    hu16[row * 512 + ((c & ~1) << 1) + (c & 1)] = f2bf(acc[r]);
                } else if (slab < 4) {
                    int c = col - 128;
                    huf[row * 256 + 128 + c] = acc[r];
                } else {
                    int c = col - 256;
                    hu16[row * 512 + ((c & ~1) << 1) + 2 + (c & 1)] = f2bf(acc[r]);
                }
            }
        }
    }
}

// ---------------- GAT aggregation: one wave per dst node, online softmax ----------------
// per edge: ONE uint2 (8 B) load per lane -> (h pair, uj pair) bf16; ui fp32 per node.
__global__ void gat_agg(const void* __restrict__ hu,
                        const int* __restrict__ rowptr, const int* __restrict__ col,
                        const float* __restrict__ resid,
                        float* __restrict__ out, int N) {
    int wid = (int)((blockIdx.x * blockDim.x + threadIdx.x) >> 6);
    if (wid >= N) return;
    int lane = threadIdx.x & 63;
    const uint2* P = (const uint2*)hu;    // row stride 128 uint2
    const float2* U = (const float2*)hu;  // row stride 128 float2, ui at +64

    float2 uiv = U[(size_t)wid * 128 + 64 + lane];
    uint2 sp = P[(size_t)wid * 128 + lane];
    float2 hs = bfpair(sp.x);
    float2 ujs = bfpair(sp.y);

    float a0 = uiv.x + ujs.x; a0 = a0 > 0.f ? a0 : 0.2f * a0;
    float a1 = uiv.y + ujs.y; a1 = a1 > 0.f ? a1 : 0.2f * a1;
    float m0 = a0, m1 = a1, l0 = 1.f, l1 = 1.f;
    float acc0 = hs.x, acc1 = hs.y;

#define AGG_STEP(pk)                                                      \
    {                                                                     \
        float2 hj = bfpair(pk.x);                                         \
        float2 uj = bfpair(pk.y);                                         \
        float b0 = uiv.x + uj.x; b0 = b0 > 0.f ? b0 : 0.2f * b0;          \
        float b1 = uiv.y + uj.y; b1 = b1 > 0.f ? b1 : 0.2f * b1;          \
        float n0 = fmaxf(m0, b0), n1 = fmaxf(m1, b1);                     \
        float s0 = __expf(m0 - n0), s1 = __expf(m1 - n1);                 \
        float p0 = __expf(b0 - n0), p1 = __expf(b1 - n1);                 \
        l0 = l0 * s0 + p0;            l1 = l1 * s1 + p1;                  \
        acc0 = acc0 * s0 + hj.x * p0; acc1 = acc1 * s1 + hj.y * p1;       \
        m0 = n0; m1 = n1;                                                 \
    }

    int e = rowptr[wid], end = rowptr[wid + 1];
    for (; e + 4 <= end; e += 4) {
        int sA = col[e], sB = col[e + 1], sC = col[e + 2], sD = col[e + 3];
        uint2 pA = P[(size_t)sA * 128 + lane];
        uint2 pB = P[(size_t)sB * 128 + lane];
        uint2 pC = P[(size_t)sC * 128 + lane];
        uint2 pD = P[(size_t)sD * 128 + lane];
        AGG_STEP(pA);
        AGG_STEP(pB);
        AGG_STEP(pC);
        AGG_STEP(pD);
    }
    for (; e < end; ++e) {
        int sA = col[e];
        uint2 pA = P[(size_t)sA * 128 + lane];
        AGG_STEP(pA);
    }
#undef AGG_STEP

    float o0 = acc0 / (l0 + 1e-16f);
    float o1 = acc1 / (l1 + 1e-16f);
    if (resid) {
        float2 rv = ((const float2*)resid)[(size_t)wid * 64 + lane];
        o0 += rv.x; o1 += rv.y;
    }
    ((float2*)out)[(size_t)wid * 64 + lane] = make_float2(o0, o1);
}

// ---------------- GRU (fp32, one block of 128 per batch row) ----------------
__global__ void gru_kernel(const float* __restrict__ st_, const float* __restrict__ in_,
                           const float* __restrict__ win,
                           const float* __restrict__ wz, const float* __restrict__ bz,
                           const float* __restrict__ wr, const float* __restrict__ br,
                           const float* __restrict__ wh, const float* __restrict__ bh,
                           float* __restrict__ out) {
    __shared__ float sst[ND], sib[EMB], si[ND], srs[ND];
    int b = blockIdx.x, d = threadIdx.x;
    float s = 0.f;
    for (int m = 0; m < MM; ++m) s += in_[((size_t)b * MM + m) * EMB + d];
    sib[d] = s * (1.0f / MM);
    sst[d] = st_[b * ND + d];
    __syncthreads();
    float iv = 0.f;
    for (int e = 0; e < EMB; ++e) iv += sib[e] * win[d * EMB + e];
    si[d] = iv;
    __syncthreads();
    float za = bz[d], ra = br[d];
    for (int e = 0; e < ND; ++e) {
        za += sst[e] * wz[d * 2 * ND + e] + si[e] * wz[d * 2 * ND + ND + e];
        ra += sst[e] * wr[d * 2 * ND + e] + si[e] * wr[d * 2 * ND + ND + e];
    }
    float z = 1.f / (1.f + __expf(-za));
    float r = 1.f / (1.f + __expf(-ra));
    srs[d] = r * sst[d];
    __syncthreads();
    float ha = bh[d];
    for (int e = 0; e < ND; ++e)
        ha += srs[e] * wh[d * 2 * ND + e] + si[e] * wh[d * 2 * ND + ND + e];
    float hc = tanhf(ha);
    out[b * ND + d] = (1.f - z) * sst[d] + z * hc;
}

// ---------------- heads phase 1: wave-per-node dots + elu outputs + staged scores ----------------
__global__ void heads_dots(const float* __restrict__ gx,
                           const float* __restrict__ pw_,
                           const float* __restrict__ mw_, const float* __restrict__ mb_,
                           const float* __restrict__ sw_, const float* __restrict__ sbias_,
                           float* __restrict__ scores, float* __restrict__ out) {
    int t = blockIdx.x;
    int lane = threadIdx.x & 63;
    int b = blockIdx.y * 4 + (threadIdx.x >> 6);
    const float2* g2 = (const float2*)gx;
    float2 pwv = ((const float2*)pw_)[lane];
    float2 mwv = ((const float2*)mw_)[lane];
    float2 swv = ((const float2*)sw_)[lane];
    int node = b * NN + 1 + t;
    float2 xv = g2[(size_t)node * 64 + lane];
    float dp = xv.x * pwv.x + xv.y * pwv.y;
    float dm = xv.x * mwv.x + xv.y * mwv.y;
    float ds = xv.x * swv.x + xv.y * swv.y;
    for (int off = 32; off; off >>= 1) {
        dp += __shfl_xor(dp, off);
        dm += __shfl_xor(dm, off);
        ds += __shfl_xor(ds, off);
    }
    if (lane == 0) {
        scores[(size_t)b * (NN - 1) + t] = dp;  // pb cancels in softmax
        float av = dm + mb_[0]; av = av > 0.f ? av : (__expf(av) - 1.f);
        float bv = fabsf(ds + sbias_[0]);       // elu(|x|) == |x|
        float* oA = out + BATCH * ND + (size_t)BATCH * (NN - 1);
        float* oB = oA + (size_t)BATCH * (NN - 1);
        oA[(size_t)b * (NN - 1) + t] = av + 2.f;
        oB[(size_t)b * (NN - 1) + t] = bv + 2.f;
    }
}

// ---------------- heads phase 2: softmax over 499 per batch row ----------------
__global__ void heads_softmax(const float* __restrict__ scores, float* __restrict__ out) {
    __shared__ float scs[NN - 1], red[256];
    int b = blockIdx.x, tid = threadIdx.x;
    float mx = -1e30f;
    for (int t = tid; t < NN - 1; t += 256) { float v = scores[(size_t)b * (NN - 1) + t]; scs[t] = v; mx = fmaxf(mx, v); }
    red[tid] = mx; __syncthreads();
    for (int off = 128; off; off >>= 1) { if (tid < off) red[tid] = fmaxf(red[tid], red[tid + off]); __syncthreads(); }
    mx = red[0]; __syncthreads();
    float sum = 0.f;
    for (int t = tid; t < NN - 1; t += 256) { float e = __expf(scs[t] - mx); scs[t] = e; sum += e; }
    red[tid] = sum; __syncthreads();
    for (int off = 128; off; off >>= 1) { if (tid < off) red[tid] += red[tid + off]; __syncthreads(); }
    float inv = 1.0f / red[0];
    float* oP = out + BATCH * ND + (size_t)b * (NN - 1);
    for (int t = tid; t < NN - 1; t += 256) oP[t] = scs[t] * inv;
}

extern "C" void kernel_launch(void* const* d_in, const int* in_sizes, int n_in,
                              void* d_out, int out_size, void* d_ws, size_t ws_size,
                              hipStream_t stream) {
    const float* state_ = (const float*)d_in[0];
    const float* input_ = (const float*)d_in[1];
    const float* x      = (const float*)d_in[2];
    const int* e_n  = (const int*)d_in[3];
    const int* e_r0 = (const int*)d_in[4];
    const int* e_r1 = (const int*)d_in[5];
    const float* win = (const float*)d_in[7];
    const float* wz  = (const float*)d_in[8];
    const float* bz  = (const float*)d_in[9];
    const float* wr  = (const float*)d_in[10];
    const float* br  = (const float*)d_in[11];
    const float* wh  = (const float*)d_in[12];
    const float* bh  = (const float*)d_in[13];
    const float* pw = (const float*)d_in[30];
    const float* mw = (const float*)d_in[32];
    const float* mb = (const float*)d_in[33];
    const float* sw = (const float*)d_in[34];
    const float* sb = (const float*)d_in[35];
    float* out = (float*)d_out;

    const int E = in_sizes[3] / 2;    // 256000
    const int N = in_sizes[2] / EMB;  // 32000

    char* w = (char*)d_ws;
    auto alloc = [&](size_t bytes) { char* p = w; w += (bytes + 255) & ~(size_t)255; return p; };
    int* rpbase = (int*)alloc(3 * (size_t)(N + RPAD) * sizeof(int));
    int* colbase = (int*)alloc(3 * (size_t)E * sizeof(int));
    int* tmp = (int*)alloc(3 * (size_t)N * sizeof(int));
    unsigned short* Whi[4]; unsigned short* Wlo[4]; float* Bf[4];
    for (int i = 0; i < 4; ++i) {
        Whi[i] = (unsigned short*)alloc(384 * 128 * 2);
        Wlo[i] = (unsigned short*)alloc(384 * 128 * 2);
        Bf[i]  = (float*)alloc(384 * 4);
    }
    void* hu = (void*)alloc((size_t)N * 1024);   // packed bf16 h|uj + fp32 ui
    float* ga = (float*)alloc((size_t)N * 128 * 4);
    float* gb = (float*)alloc((size_t)N * 128 * 4);
    float* gc = (float*)alloc((size_t)N * 128 * 4);
    float* scores = (float*)alloc((size_t)BATCH * (NN - 1) * 4);

    EdgePtrs ep; ep.e[0] = e_n; ep.e[1] = e_r0; ep.e[2] = e_r1;

    hipMemsetAsync(tmp, 0, 3 * (size_t)N * sizeof(int), stream);
    edge_hist3<<<dim3((E + 255) / 256, 3), 256, 0, stream>>>(ep, tmp, E, N);
    exscan3<<<3, 1024, 0, stream>>>(tmp, rpbase, N);
    hipMemsetAsync(tmp, 0, 3 * (size_t)N * sizeof(int), stream);
    edge_scatter3<<<dim3((E + 255) / 256, 3), 256, 0, stream>>>(ep, rpbase, tmp, colbase, E, N);

    WcPtrs wp;
    wp.lw[0] = (const float*)d_in[14]; wp.lb[0] = (const float*)d_in[15];
    wp.aw[0] = (const float*)d_in[16]; wp.ab[0] = (const float*)d_in[17];
    wp.lw[1] = (const float*)d_in[18]; wp.lb[1] = (const float*)d_in[19];
    wp.aw[1] = (const float*)d_in[20]; wp.ab[1] = (const float*)d_in[21];
    wp.lw[2] = (const float*)d_in[22]; wp.lb[2] = (const float*)d_in[23];
    wp.aw[2] = (const float*)d_in[24]; wp.ab[2] = (const float*)d_in[25];
    wp.lw[3] = (const float*)d_in[26]; wp.lb[3] = (const float*)d_in[27];
    wp.aw[3] = (const float*)d_in[28]; wp.ab[3] = (const float*)d_in[29];
    for (int i = 0; i < 4; ++i) { wp.Whi[i] = Whi[i]; wp.Wlo[i] = Wlo[i]; wp.Bf[i] = Bf[i]; }
    make_wc4<<<dim3(384, 4), 128, 0, stream>>>(wp);

    gru_kernel<<<BATCH, ND, 0, stream>>>(state_, input_, win, wz, bz, wr, br, wh, bh, out);

    auto conv = [&](const float* in, int csr_i, int wi, const float* resid, float* o) {
        lin_fused<<<dim3(64, 6), 256, 0, stream>>>(in, Whi[wi], Wlo[wi], Bf[wi], hu, N);
        gat_agg<<<(N * 64) / 256, 256, 0, stream>>>(hu, rpbase + (size_t)csr_i * (N + RPAD),
                                                    colbase + (size_t)csr_i * E, resid, o, N);
    };

    conv(x,  0, 0, nullptr, ga);  // g0 (e_n)
    conv(ga, 2, 1, nullptr, gb);  // g1 (e_r1)
    conv(gb, 2, 1, nullptr, gc);  // g2 (e_r1, g1 weights)
    conv(gc, 0, 3, ga,      gb);  // g3 = conv(g2, e_n, gn) + g0
    conv(gb, 1, 2, nullptr, gc);  // g4 (e_r0, g2 weights)
    conv(gc, 1, 2, nullptr, ga);  // g5 (e_r0, g2 weights)
    conv(ga, 0, 3, gb,      gc);  // gx = conv(g5, e_n, gn) + g3

    heads_dots<<<dim3(NN - 1, 16), 256, 0, stream>>>(gc, pw, mw, mb, sw, sb, scores, out);
    heads_softmax<<<BATCH, 256, 0, stream>>>(scores, out);
}

// Round 6
// 660.994 us; speedup vs baseline: 1.8893x; 1.0000x over previous
//
#include <hip/hip_runtime.h>
#include <hip/hip_bf16.h>

#define ND 128
#define EMB 128
#define BATCH 64
#define MM 20
#define NN 500
#define RPAD 8   // rowptr row stride padding so each row is 16-B aligned

typedef short bf16x8 __attribute__((ext_vector_type(8)));
typedef float f32x4 __attribute__((ext_vector_type(4)));

__device__ __forceinline__ float bf2f(unsigned short u) {
    union { unsigned int i; float f; } x; x.i = ((unsigned int)u) << 16; return x.f;
}
__device__ __forceinline__ unsigned short f2bf(float f) {
    union { float f; unsigned int i; } x; x.f = f;
    unsigned int r = x.i + 0x7fffu + ((x.i >> 16) & 1u);
    return (unsigned short)(r >> 16);
}
__device__ __forceinline__ float2 bfpair(unsigned int p) {
    union { unsigned int i; float f; } a, b;
    a.i = p << 16; b.i = p & 0xffff0000u;
    return make_float2(a.f, b.f);
}

// ---------------- CSR build (fused over the 3 edge lists) ----------------
struct EdgePtrs { const int* e[3]; };

__global__ void edge_hist3(EdgePtrs ep, int* __restrict__ cnt, int E, int N) {
    int li = blockIdx.y;
    const int* dst = ep.e[li] + E;
    int e = blockIdx.x * blockDim.x + threadIdx.x;
    if (e < E) atomicAdd(&cnt[(size_t)li * N + dst[e]], 1);
}

// vectorized + wave-shuffle exclusive scan; grid = 3 blocks x 1024 threads.
__global__ void exscan3(const int* __restrict__ cnt, int* __restrict__ rowptr, int n) {
    __shared__ int wsum[16];
    __shared__ int woff[16];
    int li = blockIdx.x;
    const int4* c4 = (const int4*)(cnt + (size_t)li * n);
    int* rp = rowptr + (size_t)li * (n + RPAD);
    int t = threadIdx.x;
    int lane = t & 63, wid = t >> 6;
    int n4 = n >> 2;  // n % 4 == 0

    int4 v[8];
    int s = 0;
#pragma unroll
    for (int i = 0; i < 8; ++i) {
        int idx = t * 8 + i;
        if (idx < n4) v[i] = c4[idx];
        else { v[i].x = v[i].y = v[i].z = v[i].w = 0; }
    }
#pragma unroll
    for (int i = 0; i < 8; ++i) s += v[i].x + v[i].y + v[i].z + v[i].w;

    int ps = s;
#pragma unroll
    for (int d = 1; d < 64; d <<= 1) {
        int u = __shfl_up(ps, d, 64);
        if (lane >= d) ps += u;
    }
    if (lane == 63) wsum[wid] = ps;
    __syncthreads();
    if (t == 0) {
        int r = 0;
        for (int i = 0; i < 16; ++i) { woff[i] = r; r += wsum[i]; }
    }
    __syncthreads();
    int run = woff[wid] + ps - s;
    int4* rp4 = (int4*)rp;
#pragma unroll
    for (int i = 0; i < 8; ++i) {
        int idx = t * 8 + i;
        if (idx < n4) {
            int4 o;
            o.x = run; run += v[i].x;
            o.y = run; run += v[i].y;
            o.z = run; run += v[i].z;
            o.w = run; run += v[i].w;
            rp4[idx] = o;
        }
    }
    if (t == (n - 1) / 32) rp[n] = run;
}

// countdown scatter: consumes the histogram (cnt) in place, no fill array / no 2nd memset.
__global__ void edge_scatter3(EdgePtrs ep, const int* __restrict__ rowptr, int* __restrict__ cnt,
                              int* __restrict__ col, int E, int N) {
    int li = blockIdx.y;
    const int* src = ep.e[li];
    const int* dst = src + E;
    const int* rp = rowptr + (size_t)li * (N + RPAD);
    int e = blockIdx.x * blockDim.x + threadIdx.x;
    if (e < E) {
        int d = dst[e];
        int p = atomicSub(&cnt[(size_t)li * N + d], 1) - 1;
        __builtin_nontemporal_store(src[e], &col[(size_t)li * E + rp[d] + p]);
    }
}

// ---------------- fused weight build (all 4 weight sets in one launch) ----------------
struct WcPtrs {
    const float* lw[4]; const float* lb[4]; const float* aw[4]; const float* ab[4];
    unsigned short* Whi[4]; unsigned short* Wlo[4]; float* Bf[4];
};

__global__ void make_wc4(WcPtrs p) {
    int set = blockIdx.y;
    const float* lw = p.lw[set]; const float* lb = p.lb[set];
    const float* aw = p.aw[set]; const float* ab = p.ab[set];
    int n = blockIdx.x;   // 0..383
    int e = threadIdx.x;  // 0..127
    float w;
    if (n < 128) {
        w = lw[n * 128 + e];
    } else if (n < 256) {
        int ni = n - 128; float s = 0.f;
        for (int k = 0; k < 128; ++k) s += aw[ni * 256 + k] * lw[k * 128 + e];
        w = s;
    } else {
        int nj = n - 256; float s = 0.f;
        for (int k = 0; k < 128; ++k) s += aw[nj * 256 + 128 + k] * lw[k * 128 + e];
        w = s;
    }
    unsigned short hi = f2bf(w);
    p.Whi[set][n * 128 + e] = hi;
    p.Wlo[set][n * 128 + e] = f2bf(w - bf2f(hi));
    if (e == 0) {
        float b;
        if (n < 128) b = lb[n];
        else if (n < 256) {
            int ni = n - 128; float s = ab[ni];
            for (int k = 0; k < 128; ++k) s += aw[ni * 256 + k] * lb[k];
            b = s;
        } else {
            int nj = n - 256; float s = 0.f;
            for (int k = 0; k < 128; ++k) s += aw[nj * 256 + 128 + k] * lb[k];
            b = s;
        }
        p.Bf[set][n] = b;
    }
}

// ---------------- fused GEMM into packed hu ----------------
// Block = 384 threads = 6 waves; wave w handles slab w (64 output cols). All 6 waves
// walk the SAME tile sequence -> the 5 repeat X-tile reads hit L1/L2 (X fetched once).
// hu row (1024 B): P slab = 256 bf16 shorts, 64 groups [h2l,h2l+1,uj2l,uj2l+1];
//                  U slab = 128 fp32 floats (ui', incl ab).
// Split-precision: acc += Xhi*Whi + Xlo*Whi + Xhi*Wlo  (~fp32 exact).
__launch_bounds__(384)
__global__ void lin_fused(const float* __restrict__ X,
                          const unsigned short* __restrict__ Whi,
                          const unsigned short* __restrict__ Wlo,
                          const float* __restrict__ bias,
                          void* __restrict__ hu, int M) {
    const int slab = threadIdx.x >> 6;  // 0..5: 0,1=h  2,3=ui  4,5=uj
    const int lane = threadIdx.x & 63;
    const int r16 = lane & 15;
    const int quad = lane >> 4;

    unsigned short* hu16 = (unsigned short*)hu;  // row stride 512 shorts
    float* huf = (float*)hu;                     // row stride 256 floats

    const unsigned short* Wh = Whi + (size_t)slab * 64 * 128;
    const unsigned short* Wl = Wlo + (size_t)slab * 64 * 128;
    bf16x8 wh[4][4], wl[4][4];
#pragma unroll
    for (int nt = 0; nt < 4; ++nt)
#pragma unroll
        for (int ks = 0; ks < 4; ++ks) {
            wh[nt][ks] = *(const bf16x8*)(Wh + (nt * 16 + r16) * 128 + ks * 32 + quad * 8);
            wl[nt][ks] = *(const bf16x8*)(Wl + (nt * 16 + r16) * 128 + ks * 32 + quad * 8);
        }
    float bv[4];
#pragma unroll
    for (int nt = 0; nt < 4; ++nt) bv[nt] = bias[slab * 64 + nt * 16 + r16];

    const int mt_count = M >> 4;
    for (int mt = blockIdx.x; mt < mt_count; mt += gridDim.x) {
        bf16x8 ah[4], al[4];
#pragma unroll
        for (int ks = 0; ks < 4; ++ks) {
            const float* xp = X + (size_t)(mt * 16 + r16) * 128 + ks * 32 + quad * 8;
            float4 v0 = *(const float4*)xp;
            float4 v1 = *(const float4*)(xp + 4);
            float v[8] = {v0.x, v0.y, v0.z, v0.w, v1.x, v1.y, v1.z, v1.w};
#pragma unroll
            for (int j = 0; j < 8; ++j) {
                unsigned short h = f2bf(v[j]);
                ah[ks][j] = (short)h;
                al[ks][j] = (short)f2bf(v[j] - bf2f(h));
            }
        }
#pragma unroll
        for (int nt = 0; nt < 4; ++nt) {
            f32x4 acc = {bv[nt], bv[nt], bv[nt], bv[nt]};
#pragma unroll
            for (int ks = 0; ks < 4; ++ks) {
                acc = __builtin_amdgcn_mfma_f32_16x16x32_bf16(ah[ks], wh[nt][ks], acc, 0, 0, 0);
                acc = __builtin_amdgcn_mfma_f32_16x16x32_bf16(al[ks], wh[nt][ks], acc, 0, 0, 0);
                acc = __builtin_amdgcn_mfma_f32_16x16x32_bf16(ah[ks], wl[nt][ks], acc, 0, 0, 0);
            }
            int col = slab * 64 + nt * 16 + r16;
#pragma unroll
            for (int r = 0; r < 4; ++r) {
                size_t row = (size_t)(mt * 16 + quad * 4 + r);
                if (slab < 2) {
                    int c = col;
                    hu16[row * 512 + ((c & ~1) << 1) + (c & 1)] = f2bf(acc[r]);
                } else if (slab < 4) {
                    int c = col - 128;
                    huf[row * 256 + 128 + c] = acc[r];
                } else {
                    int c = col - 256;
                    hu16[row * 512 + ((c & ~1) << 1) + 2 + (c & 1)] = f2bf(acc[r]);
                }
            }
        }
    }
}

// ---------------- GAT aggregation: one wave per dst node, online softmax ----------------
// per edge: ONE uint2 (8 B) load per lane -> (h pair, uj pair) bf16; ui fp32 per node.
__global__ void gat_agg(const void* __restrict__ hu,
                        const int* __restrict__ rowptr, const int* __restrict__ col,
                        const float* __restrict__ resid,
                        float* __restrict__ out, int N) {
    int wid = (int)((blockIdx.x * blockDim.x + threadIdx.x) >> 6);
    if (wid >= N) return;
    int lane = threadIdx.x & 63;
    const uint2* P = (const uint2*)hu;    // row stride 128 uint2
    const float2* U = (const float2*)hu;  // row stride 128 float2, ui at +64

    float2 uiv = U[(size_t)wid * 128 + 64 + lane];
    uint2 sp = P[(size_t)wid * 128 + lane];
    float2 hs = bfpair(sp.x);
    float2 ujs = bfpair(sp.y);

    float a0 = uiv.x + ujs.x; a0 = a0 > 0.f ? a0 : 0.2f * a0;
    float a1 = uiv.y + ujs.y; a1 = a1 > 0.f ? a1 : 0.2f * a1;
    float m0 = a0, m1 = a1, l0 = 1.f, l1 = 1.f;
    float acc0 = hs.x, acc1 = hs.y;

#define AGG_STEP(pk)                                                      \
    {                                                                     \
        float2 hj = bfpair(pk.x);                                         \
        float2 uj = bfpair(pk.y);                                         \
        float b0 = uiv.x + uj.x; b0 = b0 > 0.f ? b0 : 0.2f * b0;          \
        float b1 = uiv.y + uj.y; b1 = b1 > 0.f ? b1 : 0.2f * b1;          \
        float n0 = fmaxf(m0, b0), n1 = fmaxf(m1, b1);                     \
        float s0 = __expf(m0 - n0), s1 = __expf(m1 - n1);                 \
        float p0 = __expf(b0 - n0), p1 = __expf(b1 - n1);                 \
        l0 = l0 * s0 + p0;            l1 = l1 * s1 + p1;                  \
        acc0 = acc0 * s0 + hj.x * p0; acc1 = acc1 * s1 + hj.y * p1;       \
        m0 = n0; m1 = n1;                                                 \
    }

    int e = rowptr[wid], end = rowptr[wid + 1];
    for (; e + 4 <= end; e += 4) {
        int sA = col[e], sB = col[e + 1], sC = col[e + 2], sD = col[e + 3];
        uint2 pA = P[(size_t)sA * 128 + lane];
        uint2 pB = P[(size_t)sB * 128 + lane];
        uint2 pC = P[(size_t)sC * 128 + lane];
        uint2 pD = P[(size_t)sD * 128 + lane];
        AGG_STEP(pA);
        AGG_STEP(pB);
        AGG_STEP(pC);
        AGG_STEP(pD);
    }
    for (; e < end; ++e) {
        int sA = col[e];
        uint2 pA = P[(size_t)sA * 128 + lane];
        AGG_STEP(pA);
    }
#undef AGG_STEP

    float o0 = acc0 / (l0 + 1e-16f);
    float o1 = acc1 / (l1 + 1e-16f);
    if (resid) {
        float2 rv = ((const float2*)resid)[(size_t)wid * 64 + lane];
        o0 += rv.x; o1 += rv.y;
    }
    ((float2*)out)[(size_t)wid * 64 + lane] = make_float2(o0, o1);
}

// ---------------- GRU (fp32, one block of 128 per batch row) ----------------
__global__ void gru_kernel(const float* __restrict__ st_, const float* __restrict__ in_,
                           const float* __restrict__ win,
                           const float* __restrict__ wz, const float* __restrict__ bz,
                           const float* __restrict__ wr, const float* __restrict__ br,
                           const float* __restrict__ wh, const float* __restrict__ bh,
                           float* __restrict__ out) {
    __shared__ float sst[ND], sib[EMB], si[ND], srs[ND];
    int b = blockIdx.x, d = threadIdx.x;
    float s = 0.f;
    for (int m = 0; m < MM; ++m) s += in_[((size_t)b * MM + m) * EMB + d];
    sib[d] = s * (1.0f / MM);
    sst[d] = st_[b * ND + d];
    __syncthreads();
    float iv = 0.f;
    for (int e = 0; e < EMB; ++e) iv += sib[e] * win[d * EMB + e];
    si[d] = iv;
    __syncthreads();
    float za = bz[d], ra = br[d];
    for (int e = 0; e < ND; ++e) {
        za += sst[e] * wz[d * 2 * ND + e] + si[e] * wz[d * 2 * ND + ND + e];
        ra += sst[e] * wr[d * 2 * ND + e] + si[e] * wr[d * 2 * ND + ND + e];
    }
    float z = 1.f / (1.f + __expf(-za));
    float r = 1.f / (1.f + __expf(-ra));
    srs[d] = r * sst[d];
    __syncthreads();
    float ha = bh[d];
    for (int e = 0; e < ND; ++e)
        ha += srs[e] * wh[d * 2 * ND + e] + si[e] * wh[d * 2 * ND + ND + e];
    float hc = tanhf(ha);
    out[b * ND + d] = (1.f - z) * sst[d] + z * hc;
}

// ---------------- heads phase 1: wave-per-node dots + elu outputs + staged scores ----------------
__global__ void heads_dots(const float* __restrict__ gx,
                           const float* __restrict__ pw_,
                           const float* __restrict__ mw_, const float* __restrict__ mb_,
                           const float* __restrict__ sw_, const float* __restrict__ sbias_,
                           float* __restrict__ scores, float* __restrict__ out) {
    int t = blockIdx.x;
    int lane = threadIdx.x & 63;
    int b = blockIdx.y * 4 + (threadIdx.x >> 6);
    const float2* g2 = (const float2*)gx;
    float2 pwv = ((const float2*)pw_)[lane];
    float2 mwv = ((const float2*)mw_)[lane];
    float2 swv = ((const float2*)sw_)[lane];
    int node = b * NN + 1 + t;
    float2 xv = g2[(size_t)node * 64 + lane];
    float dp = xv.x * pwv.x + xv.y * pwv.y;
    float dm = xv.x * mwv.x + xv.y * mwv.y;
    float ds = xv.x * swv.x + xv.y * swv.y;
    for (int off = 32; off; off >>= 1) {
        dp += __shfl_xor(dp, off);
        dm += __shfl_xor(dm, off);
        ds += __shfl_xor(ds, off);
    }
    if (lane == 0) {
        scores[(size_t)b * (NN - 1) + t] = dp;  // pb cancels in softmax
        float av = dm + mb_[0]; av = av > 0.f ? av : (__expf(av) - 1.f);
        float bv = fabsf(ds + sbias_[0]);       // elu(|x|) == |x|
        float* oA = out + BATCH * ND + (size_t)BATCH * (NN - 1);
        float* oB = oA + (size_t)BATCH * (NN - 1);
        oA[(size_t)b * (NN - 1) + t] = av + 2.f;
        oB[(size_t)b * (NN - 1) + t] = bv + 2.f;
    }
}

// ---------------- heads phase 2: softmax over 499 per batch row ----------------
__global__ void heads_softmax(const float* __restrict__ scores, float* __restrict__ out) {
    __shared__ float scs[NN - 1], red[256];
    int b = blockIdx.x, tid = threadIdx.x;
    float mx = -1e30f;
    for (int t = tid; t < NN - 1; t += 256) { float v = scores[(size_t)b * (NN - 1) + t]; scs[t] = v; mx = fmaxf(mx, v); }
    red[tid] = mx; __syncthreads();
    for (int off = 128; off; off >>= 1) { if (tid < off) red[tid] = fmaxf(red[tid], red[tid + off]); __syncthreads(); }
    mx = red[0]; __syncthreads();
    float sum = 0.f;
    for (int t = tid; t < NN - 1; t += 256) { float e = __expf(scs[t] - mx); scs[t] = e; sum += e; }
    red[tid] = sum; __syncthreads();
    for (int off = 128; off; off >>= 1) { if (tid < off) red[tid] += red[tid + off]; __syncthreads(); }
    float inv = 1.0f / red[0];
    float* oP = out + BATCH * ND + (size_t)b * (NN - 1);
    for (int t = tid; t < NN - 1; t += 256) oP[t] = scs[t] * inv;
}

extern "C" void kernel_launch(void* const* d_in, const int* in_sizes, int n_in,
                              void* d_out, int out_size, void* d_ws, size_t ws_size,
                              hipStream_t stream) {
    const float* state_ = (const float*)d_in[0];
    const float* input_ = (const float*)d_in[1];
    const float* x      = (const float*)d_in[2];
    const int* e_n  = (const int*)d_in[3];
    const int* e_r0 = (const int*)d_in[4];
    const int* e_r1 = (const int*)d_in[5];
    const float* win = (const float*)d_in[7];
    const float* wz  = (const float*)d_in[8];
    const float* bz  = (const float*)d_in[9];
    const float* wr  = (const float*)d_in[10];
    const float* br  = (const float*)d_in[11];
    const float* wh  = (const float*)d_in[12];
    const float* bh  = (const float*)d_in[13];
    const float* pw = (const float*)d_in[30];
    const float* mw = (const float*)d_in[32];
    const float* mb = (const float*)d_in[33];
    const float* sw = (const float*)d_in[34];
    const float* sb = (const float*)d_in[35];
    float* out = (float*)d_out;

    const int E = in_sizes[3] / 2;    // 256000
    const int N = in_sizes[2] / EMB;  // 32000

    char* w = (char*)d_ws;
    auto alloc = [&](size_t bytes) { char* p = w; w += (bytes + 255) & ~(size_t)255; return p; };
    int* rpbase = (int*)alloc(3 * (size_t)(N + RPAD) * sizeof(int));
    int* colbase = (int*)alloc(3 * (size_t)E * sizeof(int));
    int* tmp = (int*)alloc(3 * (size_t)N * sizeof(int));
    unsigned short* Whi[4]; unsigned short* Wlo[4]; float* Bf[4];
    for (int i = 0; i < 4; ++i) {
        Whi[i] = (unsigned short*)alloc(384 * 128 * 2);
        Wlo[i] = (unsigned short*)alloc(384 * 128 * 2);
        Bf[i]  = (float*)alloc(384 * 4);
    }
    void* hu = (void*)alloc((size_t)N * 1024);   // packed bf16 h|uj + fp32 ui
    float* ga = (float*)alloc((size_t)N * 128 * 4);
    float* gb = (float*)alloc((size_t)N * 128 * 4);
    float* gc = (float*)alloc((size_t)N * 128 * 4);
    float* scores = (float*)alloc((size_t)BATCH * (NN - 1) * 4);

    EdgePtrs ep; ep.e[0] = e_n; ep.e[1] = e_r0; ep.e[2] = e_r1;

    hipMemsetAsync(tmp, 0, 3 * (size_t)N * sizeof(int), stream);
    edge_hist3<<<dim3((E + 255) / 256, 3), 256, 0, stream>>>(ep, tmp, E, N);
    exscan3<<<3, 1024, 0, stream>>>(tmp, rpbase, N);
    edge_scatter3<<<dim3((E + 255) / 256, 3), 256, 0, stream>>>(ep, rpbase, tmp, colbase, E, N);

    WcPtrs wp;
    wp.lw[0] = (const float*)d_in[14]; wp.lb[0] = (const float*)d_in[15];
    wp.aw[0] = (const float*)d_in[16]; wp.ab[0] = (const float*)d_in[17];
    wp.lw[1] = (const float*)d_in[18]; wp.lb[1] = (const float*)d_in[19];
    wp.aw[1] = (const float*)d_in[20]; wp.ab[1] = (const float*)d_in[21];
    wp.lw[2] = (const float*)d_in[22]; wp.lb[2] = (const float*)d_in[23];
    wp.aw[2] = (const float*)d_in[24]; wp.ab[2] = (const float*)d_in[25];
    wp.lw[3] = (const float*)d_in[26]; wp.lb[3] = (const float*)d_in[27];
    wp.aw[3] = (const float*)d_in[28]; wp.ab[3] = (const float*)d_in[29];
    for (int i = 0; i < 4; ++i) { wp.Whi[i] = Whi[i]; wp.Wlo[i] = Wlo[i]; wp.Bf[i] = Bf[i]; }
    make_wc4<<<dim3(384, 4), 128, 0, stream>>>(wp);

    gru_kernel<<<BATCH, ND, 0, stream>>>(state_, input_, win, wz, bz, wr, br, wh, bh, out);

    auto conv = [&](const float* in, int csr_i, int wi, const float* resid, float* o) {
        lin_fused<<<256, 384, 0, stream>>>(in, Whi[wi], Wlo[wi], Bf[wi], hu, N);
        gat_agg<<<(N * 64) / 256, 256, 0, stream>>>(hu, rpbase + (size_t)csr_i * (N + RPAD),
                                                    colbase + (size_t)csr_i * E, resid, o, N);
    };

    conv(x,  0, 0, nullptr, ga);  // g0 (e_n)
    conv(ga, 2, 1, nullptr, gb);  // g1 (e_r1)
    conv(gb, 2, 1, nullptr, gc);  // g2 (e_r1, g1 weights)
    conv(gc, 0, 3, ga,      gb);  // g3 = conv(g2, e_n, gn) + g0
    conv(gb, 1, 2, nullptr, gc);  // g4 (e_r0, g2 weights)
    conv(gc, 1, 2, nullptr, ga);  // g5 (e_r0, g2 weights)
    conv(ga, 0, 3, gb,      gc);  // gx = conv(g5, e_n, gn) + g3

    heads_dots<<<dim3(NN - 1, 16), 256, 0, stream>>>(gc, pw, mw, mb, sw, sb, scores, out);
    heads_softmax<<<BATCH, 256, 0, stream>>>(scores, out);
}